// Round 7
// baseline (3535.428 us; speedup 1.0000x reference)
//
#include <hip/hip_runtime.h>
#include <cstdint>

#define VV     50257
#define VPAD   50432   // 197 * 256
#define DMODEL 768
#define NLAYER 4
#define DINNER 1536
#define DSTATE 16
#define DCONV  4
#define BATCH  2
#define SEQ    512
#define MROWS  (BATCH*SEQ)   // 1024
#define NBLK   512           // co-residency GUARANTEED: launch_bounds(256,2) caps VGPR<=256
                             // -> 2 blocks/CU by VGPR; 48KB LDS -> 3/CU; 2*256 = 512.

typedef unsigned short u16;
typedef __attribute__((ext_vector_type(8))) short bf16x8;
typedef __attribute__((ext_vector_type(4))) float f32x4;

__device__ __forceinline__ u16 f2bf(float f) {
  unsigned u = __float_as_uint(f);
  u += 0x7fffu + ((u >> 16) & 1u);
  return (u16)(u >> 16);
}

__device__ __forceinline__ void async16(const void* g, void* l) {
  auto gp = reinterpret_cast<const __attribute__((address_space(1))) unsigned int*>(
      reinterpret_cast<uintptr_t>(g));
  auto lp = reinterpret_cast<__attribute__((address_space(3))) unsigned int*>(
      reinterpret_cast<uintptr_t>(l));
  __builtin_amdgcn_global_load_lds(gp, lp, 16, 0, 0);
}

// ---------------------------------------------------------------- grid barrier
// bar[0]=cnt, bar[1]=gen (zeroed by prep_kern each call). Bounded spin failsafe:
// if co-residency were ever violated we finish (wrong) instead of hanging the queue.
__device__ __forceinline__ void gridbar(int* bar) {
  __syncthreads();
  if (threadIdx.x == 0) {
    __threadfence();
    int g = __hip_atomic_load(&bar[1], __ATOMIC_ACQUIRE, __HIP_MEMORY_SCOPE_AGENT);
    int a = __hip_atomic_fetch_add(&bar[0], 1, __ATOMIC_ACQ_REL, __HIP_MEMORY_SCOPE_AGENT);
    if (a == NBLK - 1) {
      __hip_atomic_store(&bar[0], 0, __ATOMIC_RELAXED, __HIP_MEMORY_SCOPE_AGENT);
      __hip_atomic_fetch_add(&bar[1], 1, __ATOMIC_ACQ_REL, __HIP_MEMORY_SCOPE_AGENT);
    } else {
      int spins = 0;
      while (__hip_atomic_load(&bar[1], __ATOMIC_ACQUIRE, __HIP_MEMORY_SCOPE_AGENT) == g) {
        __builtin_amdgcn_s_sleep(8);
        if (++spins > (1 << 27)) break;
      }
    }
    __threadfence();
  }
  __syncthreads();
}

// ---------------------------------------------------------------- fused prep (+ bar zeroing)
__global__ void prep_kern(const float* __restrict__ emb, const float* __restrict__ W_in,
                          const float* __restrict__ W_out, const int* __restrict__ idx,
                          u16* __restrict__ embbf, u16* __restrict__ winbf,
                          u16* __restrict__ woutbf, float* __restrict__ xf,
                          u16* __restrict__ xbf, int* __restrict__ bar) {
  if (blockIdx.x == 0 && threadIdx.x == 0) { bar[0] = 0; bar[1] = 0; }
  const int E4  = VPAD * DMODEL / 4;
  const int W14 = NLAYER * 2 * DINNER * DMODEL / 4;
  const int W24 = NLAYER * DMODEL * DINNER / 4;
  const int X4  = MROWS * DMODEL / 4;
  const int TOT = E4 + W14 + W24 + X4;
  int i = blockIdx.x * blockDim.x + threadIdx.x;
  const int stride = gridDim.x * blockDim.x;
  for (; i < TOT; i += stride) {
    if (i < E4) {
      ushort4 o;
      if (i < VV * DMODEL / 4) {
        float4 v = *(const float4*)(emb + (long)i * 4);
        o.x = f2bf(v.x); o.y = f2bf(v.y); o.z = f2bf(v.z); o.w = f2bf(v.w);
      } else { o.x = 0; o.y = 0; o.z = 0; o.w = 0; }
      *(ushort4*)(embbf + (long)i * 4) = o;
    } else if (i < E4 + W14) {
      const int j = i - E4;
      float4 v = *(const float4*)(W_in + (long)j * 4);
      ushort4 o; o.x = f2bf(v.x); o.y = f2bf(v.y); o.z = f2bf(v.z); o.w = f2bf(v.w);
      *(ushort4*)(winbf + (long)j * 4) = o;
    } else if (i < E4 + W14 + W24) {
      const int j = i - E4 - W14;
      float4 v = *(const float4*)(W_out + (long)j * 4);
      ushort4 o; o.x = f2bf(v.x); o.y = f2bf(v.y); o.z = f2bf(v.z); o.w = f2bf(v.w);
      *(ushort4*)(woutbf + (long)j * 4) = o;
    } else {
      const int j = i - E4 - W14 - W24;
      const int r = j / (DMODEL / 4);
      const int c = (j % (DMODEL / 4)) * 4;
      const int id = idx[r];
      float4 v = *(const float4*)(emb + (long)id * DMODEL + c);
      *(float4*)(xf + (long)r * DMODEL + c) = v;
      ushort4 o; o.x = f2bf(v.x); o.y = f2bf(v.y); o.z = f2bf(v.z); o.w = f2bf(v.w);
      *(ushort4*)(xbf + (long)r * DMODEL + c) = o;
    }
  }
}

// ---------------------------------------------------------------- 128^2 ring-3 GEMM body (device fn)
__device__ __forceinline__ void gemm128(
    const u16* __restrict__ A, const u16* __restrict__ B, float* __restrict__ C,
    int N, int K, int lda, int ldb, int koff, int bx, int by, char* smem)
{
  u16* As = (u16*)smem;                 // 3 * 128*32 u16 = 24576 B
  u16* Bs = (u16*)(smem + 24576);
  const int tid  = threadIdx.x;
  const int wave = tid >> 6;
  const int lane = tid & 63;
  const int wr = wave >> 1, wc = wave & 1;
  const int m0 = bx * 128;
  const int n0 = by * 128;

  const int srow = wave * 32 + (lane >> 2);
  const int sblk = ((lane & 3) ^ ((lane >> 3) & 3)) * 8;

  f32x4 acc[4][4];
#pragma unroll
  for (int i = 0; i < 4; ++i)
#pragma unroll
    for (int j = 0; j < 4; ++j) acc[i][j] = (f32x4){0.f, 0.f, 0.f, 0.f};

  const int arow = wr * 64 + (lane & 15);
  const int brow = wc * 64 + (lane & 15);
  const int sa   = (((lane >> 4) ^ ((lane >> 1) & 3)) << 3);

  const int KT = K / 32;
  auto stage = [&](int kt) {
    const int slot = kt % 3;
    const long kcol = (long)koff + kt * 32;
#pragma unroll
    for (int j = 0; j < 2; ++j) {
      async16(A + (long)(m0 + srow + j * 16) * lda + kcol + sblk,
              As + slot * 128 * 32 + (wave * 32 + j * 16) * 32);
      async16(B + (long)(n0 + srow + j * 16) * ldb + kcol + sblk,
              Bs + slot * 128 * 32 + (wave * 32 + j * 16) * 32);
    }
  };

  asm volatile("s_waitcnt vmcnt(0)" ::: "memory");
  stage(0);
  stage(1);
  for (int t = 0; t < KT; ++t) {
    if (t + 2 < KT) {
      stage(t + 2);
      asm volatile("s_waitcnt vmcnt(8)" ::: "memory");
    } else if (t + 2 == KT) {
      asm volatile("s_waitcnt vmcnt(4)" ::: "memory");
    } else {
      asm volatile("s_waitcnt vmcnt(0)" ::: "memory");
    }
    __builtin_amdgcn_s_barrier();
    asm volatile("" ::: "memory");

    const u16* as = As + (t % 3) * 128 * 32;
    const u16* bs = Bs + (t % 3) * 128 * 32;
    bf16x8 af[4], bv[4];
#pragma unroll
    for (int i = 0; i < 4; ++i) af[i] = *(const bf16x8*)(as + (arow + 16 * i) * 32 + sa);
#pragma unroll
    for (int j = 0; j < 4; ++j) bv[j] = *(const bf16x8*)(bs + (brow + 16 * j) * 32 + sa);

    __builtin_amdgcn_s_setprio(1);
#pragma unroll
    for (int i = 0; i < 4; ++i)
#pragma unroll
      for (int j = 0; j < 4; ++j)
        acc[i][j] = __builtin_amdgcn_mfma_f32_16x16x32_bf16(af[i], bv[j], acc[i][j], 0, 0, 0);
    __builtin_amdgcn_s_setprio(0);

    asm volatile("" ::: "memory");
    __builtin_amdgcn_s_barrier();
    asm volatile("" ::: "memory");
  }

  const int rbase = m0 + wr * 64 + ((lane >> 4) << 2);
  const int cbase = n0 + wc * 64 + (lane & 15);
#pragma unroll
  for (int j = 0; j < 4; ++j) {
    const int col = cbase + j * 16;
#pragma unroll
    for (int i = 0; i < 4; ++i) {
#pragma unroll
      for (int r = 0; r < 4; ++r) {
        const int row = rbase + i * 16 + r;
        C[(long)row * N + col] = acc[i][j][r];
      }
    }
  }
}

// ---------------------------------------------------------------- megakernel: 4 layers + RMS
// part buffer double-duty: phase1 split-K2 second partial lives in part (M*3072 f32
// == 4*M*768 f32, dead until phase4 overwrites it after phase3 consumed it).
__global__ __launch_bounds__(256, 2) void mega_kern(
    const float* __restrict__ convw, const float* __restrict__ W_xp,
    const float* __restrict__ W_dt, const float* __restrict__ b_dt,
    const float* __restrict__ a_log, const float* __restrict__ d_par,
    const float* __restrict__ normw,
    const u16* __restrict__ winbf, const u16* __restrict__ woutbf,
    u16* __restrict__ xbf, float* __restrict__ xf,
    float* __restrict__ xz0,
    float* __restrict__ xs, float* __restrict__ dlt, float* __restrict__ bc,
    u16* __restrict__ ybf, u16* __restrict__ xnbf,
    float* __restrict__ part, int* __restrict__ bar)
{
  __shared__ __align__(16) char smem[49152];
  const int bid = blockIdx.x;
  const int tid = threadIdx.x;

#pragma unroll 1
  for (int l = 0; l < NLAYER; ++l) {
    // ===== phase 1: xz = x @ W_in^T, split-K x2 (384 tasks); ks1 -> part =====
    if (bid < 384) {
      const int ks = bid & 1, t = bid >> 1;          // t: 0..191
      gemm128(xbf, winbf + (size_t)l * 2 * DINNER * DMODEL, ks ? part : xz0,
              2 * DINNER, DMODEL / 2, DMODEL, DMODEL, ks * (DMODEL / 2),
              t & 7, t >> 3, smem);
    }
    gridbar(bar);

    // ===== phase 2: conv + SiLU + xproj + delta (2 rows/block) =====
    {
      float* sx  = (float*)smem;
      float* sxp = (float*)(smem + DINNER * 4);
      const float* cw  = convw + (size_t)l * DINNER * DCONV;
      const float* Wx  = W_xp + (size_t)l * (2 * DSTATE + 1) * DINNER;
      const float* wdt = W_dt + (size_t)l * DINNER;
      const float* bdt = b_dt + (size_t)l * DINNER;
#pragma unroll 1
      for (int rr = 0; rr < 2; ++rr) {
        const int row = bid * 2 + rr;
        const int trow = row & (SEQ - 1);
        for (int c = tid; c < DINNER; c += 256) {
          const float* w = cw + c * DCONV;
          float a = 0.f;
#pragma unroll
          for (int k = 0; k < DCONV; ++k) {
            const int tt = trow - (DCONV - 1) + k;
            if (tt >= 0) {
              const long ix = (long)(row - (DCONV - 1) + k) * (2 * DINNER) + c;
              a += w[k] * (xz0[ix] + part[ix]);
            }
          }
          const float s = a / (1.f + __expf(-a));
          sx[c] = s;
          xs[(long)row * DINNER + c] = s;
        }
        __syncthreads();
        const int wv = tid >> 6, lane = tid & 63;
        for (int e = wv; e < 2 * DSTATE + 1; e += 4) {
          const float* We = Wx + (long)e * DINNER;
          float p = 0.f;
          for (int d = lane; d < DINNER; d += 64) p += sx[d] * We[d];
#pragma unroll
          for (int off2 = 32; off2; off2 >>= 1) p += __shfl_xor(p, off2, 64);
          if (lane == 0) sxp[e] = p;
        }
        __syncthreads();
        const float dtr = sxp[0];
        for (int d = tid; d < DINNER; d += 256) {
          float v = dtr * wdt[d] + bdt[d];
          float sp = (v > 15.f) ? v : log1pf(__expf(v));
          dlt[(long)row * DINNER + d] = sp;
        }
        if (tid < 2 * DSTATE) bc[(long)row * (2 * DSTATE) + tid] = sxp[1 + tid];
        __syncthreads();
      }
    }
    gridbar(bar);

    // ===== phase 3: chunked scan + gate (384 tasks, 32 chunks x 16 steps) =====
    if (bid < 384) {
      float (*sh_h)[8][DSTATE] = (float(*)[8][DSTATE])smem;       // 16 KB
      float (*sh_s)[8]         = (float(*)[8])(smem + 16384);
      const float* alog = a_log + (size_t)l * DINNER * DSTATE;
      const float* dpar = d_par + (size_t)l * DINNER;
      const int ch = tid & 7, chunk = tid >> 3;       // chunk 0..31
      const int ch_abs = bid * 8 + ch;
      const int b = ch_abs / DINNER, d = ch_abs % DINNER;
      float An[DSTATE];
#pragma unroll
      for (int n = 0; n < DSTATE; ++n) An[n] = -__expf(alog[(long)d * DSTATE + n]);
      const int r0 = b * SEQ + chunk * 16;

      float h[DSTATE];
#pragma unroll
      for (int n = 0; n < DSTATE; ++n) h[n] = 0.f;
      float ssum = 0.f;
      for (int s = 0; s < 16; ++s) {
        const int row = r0 + s;
        const float dl = dlt[(long)row * DINNER + d];
        const float xv = xs[(long)row * DINNER + d];
        const float dx = dl * xv;
        const float4* bp = (const float4*)(bc + (long)row * (2 * DSTATE));
        float Bv[DSTATE];
        *(float4*)&Bv[0] = bp[0]; *(float4*)&Bv[4] = bp[1];
        *(float4*)&Bv[8] = bp[2]; *(float4*)&Bv[12] = bp[3];
        ssum += dl;
#pragma unroll
        for (int n = 0; n < DSTATE; ++n) h[n] = __expf(dl * An[n]) * h[n] + dx * Bv[n];
      }
#pragma unroll
      for (int n = 0; n < DSTATE; ++n) sh_h[chunk][ch][n] = h[n];
      sh_s[chunk][ch] = ssum;
      __syncthreads();

      if (tid < 128) {
        const int n2 = tid & 15, ch2 = tid >> 4;
        const int d2 = (bid * 8 + ch2) % DINNER;
        const float A2 = -__expf(alog[(long)d2 * DSTATE + n2]);
        float carry = 0.f;
        for (int c = 0; c < 32; ++c) {
          const float hl = sh_h[c][ch2][n2];
          sh_h[c][ch2][n2] = carry;
          carry = __expf(A2 * sh_s[c][ch2]) * carry + hl;
        }
      }
      __syncthreads();

#pragma unroll
      for (int n = 0; n < DSTATE; ++n) h[n] = sh_h[chunk][ch][n];
      const float dp = dpar[d];
      for (int s = 0; s < 16; ++s) {
        const int row = r0 + s;
        const float dl = dlt[(long)row * DINNER + d];
        const float xv = xs[(long)row * DINNER + d];
        const float dx = dl * xv;
        const float4* bp = (const float4*)(bc + (long)row * (2 * DSTATE));
        float Bv[DSTATE], Cv[DSTATE];
        *(float4*)&Bv[0] = bp[0]; *(float4*)&Bv[4] = bp[1];
        *(float4*)&Bv[8] = bp[2]; *(float4*)&Bv[12] = bp[3];
        *(float4*)&Cv[0] = bp[4]; *(float4*)&Cv[4] = bp[5];
        *(float4*)&Cv[8] = bp[6]; *(float4*)&Cv[12] = bp[7];
        float y = 0.f;
#pragma unroll
        for (int n = 0; n < DSTATE; ++n) {
          const float hn = __expf(dl * An[n]) * h[n] + dx * Bv[n];
          h[n] = hn;
          y += Cv[n] * hn;
        }
        y += dp * xv;
        const long zix = (long)row * (2 * DINNER) + DINNER + d;
        const float zz = xz0[zix] + part[zix];
        const float o = y * (zz / (1.f + __expf(-zz)));
        ybf[(long)row * DINNER + d] = f2bf(o);
      }
    }
    gridbar(bar);

    // ===== phase 4: out-proj split-K x4 (192 tasks) =====
    if (bid < 192) {
      const int ks = bid & 3, tile = bid >> 2;        // tile: 0..47
      gemm128(ybf, woutbf + (size_t)l * DMODEL * DINNER,
              part + (size_t)ks * MROWS * DMODEL,
              DMODEL, DINNER / 4, DINNER, DINNER, ks * (DINNER / 4),
              tile & 7, tile >> 3, smem);
    }
    gridbar(bar);

    // ===== phase 5: reduce 4 partials + residual (skip on last layer) =====
    if (l < NLAYER - 1) {
      const int stride4 = MROWS * DMODEL / 4;
      for (int i = bid * 256 + tid; i < stride4; i += NBLK * 256) {
        float4 s = ((const float4*)xf)[i];
#pragma unroll
        for (int k = 0; k < 4; ++k) {
          float4 p = ((const float4*)part)[i + k * stride4];
          s.x += p.x; s.y += p.y; s.z += p.z; s.w += p.w;
        }
        ((float4*)xf)[i] = s;
        ushort4 o; o.x = f2bf(s.x); o.y = f2bf(s.y); o.z = f2bf(s.z); o.w = f2bf(s.w);
        ((ushort4*)xbf)[i] = o;
      }
      gridbar(bar);
    }
  }

  // ===== final: 4-partial reduce + residual + RMSNorm -> bf16 (2 rows/block) =====
  {
    float* red = (float*)smem;
    const int S = MROWS * DMODEL;
#pragma unroll 1
    for (int rr = 0; rr < 2; ++rr) {
      const int row = bid * 2 + rr;
      float v[3];
      float p = 0.f;
#pragma unroll
      for (int k = 0; k < 3; ++k) {
        const int i = row * DMODEL + tid + k * 256;
        float x = xf[i];
#pragma unroll
        for (int q = 0; q < 4; ++q) x += part[i + q * S];
        v[k] = x;
        p += x * x;
      }
#pragma unroll
      for (int off2 = 32; off2; off2 >>= 1) p += __shfl_xor(p, off2, 64);
      const int wv = tid >> 6, lane = tid & 63;
      if (lane == 0) red[wv] = p;
      __syncthreads();
      if (tid == 0) {
        float tsum = red[0] + red[1] + red[2] + red[3];
        red[4] = rsqrtf(tsum / (float)DMODEL + 1e-5f);
      }
      __syncthreads();
      const float r = red[4];
#pragma unroll
      for (int k = 0; k < 3; ++k) {
        const int dd = tid + k * 256;
        xnbf[(long)row * DMODEL + dd] = f2bf(v[k] * r * normw[dd]);
      }
      __syncthreads();
    }
  }
}

// ---------------------------------------------------------------- 256^2 4-phase pipelined GEMM (logits, unchanged)
__global__ __launch_bounds__(512, 2) void gemm8_kern(
    const u16* __restrict__ A, const u16* __restrict__ B,
    float* __restrict__ C, int N, int K, int lda, int ldb)
{
  __shared__ u16 lds[2][2][256 * 64];
  const int tid = threadIdx.x;
  const int wave = tid >> 6;
  const int lane = tid & 63;
  const int wm = wave >> 2, wn = wave & 3;

  const int nwg = gridDim.x;
  const int q = nwg >> 3, r = nwg & 7;
  const int xcd = blockIdx.x & 7;
  const int t = (xcd < r ? xcd * (q + 1) : r * (q + 1) + (xcd - r) * q) + (blockIdx.x >> 3);
  const int m0 = (t & 3) * 256;
  const int n0 = (t >> 2) * 256;

  const int NT = K / 64;

  const int sblk = (((lane & 7) ^ (lane >> 3)) << 3);
  auto stage = [&](int buf, int ab, int half, int kt) {
    const u16* Mat = ab ? B : A;
    const int ld = ab ? ldb : lda;
    const int tb = ab ? n0 : m0;
#pragma unroll
    for (int j = 0; j < 2; ++j) {
      const int rloc = half * 128 + j * 64 + wave * 8;
      async16(Mat + (long)(tb + rloc + (lane >> 3)) * ld + kt * 64 + sblk,
              (char*)&lds[buf][ab][0] + (rloc << 7));
    }
  };

  bf16x8 af[4][2], bl[2][2], bh[2][2];
  const int aq = lane >> 4;
  auto readA = [&](int buf, int half) {
#pragma unroll
    for (int mf = 0; mf < 4; ++mf) {
      const int rr = half * 128 + wm * 64 + mf * 16 + (lane & 15);
#pragma unroll
      for (int ks = 0; ks < 2; ++ks) {
        const int q2 = ks * 4 + aq;
        af[mf][ks] = *(const bf16x8*)(&lds[buf][0][0] + rr * 64 + ((q2 ^ (rr & 7)) << 3));
      }
    }
  };
  auto readB = [&](int buf, int half, bf16x8 (&bf)[2][2]) {
#pragma unroll
    for (int nf = 0; nf < 2; ++nf) {
      const int rr = half * 128 + wn * 32 + nf * 16 + (lane & 15);
#pragma unroll
      for (int ks = 0; ks < 2; ++ks) {
        const int q2 = ks * 4 + aq;
        bf[nf][ks] = *(const bf16x8*)(&lds[buf][1][0] + rr * 64 + ((q2 ^ (rr & 7)) << 3));
      }
    }
  };

  f32x4 acc[8][4];
#pragma unroll
  for (int i = 0; i < 8; ++i)
#pragma unroll
    for (int j = 0; j < 4; ++j) acc[i][j] = (f32x4){0.f, 0.f, 0.f, 0.f};

#define MFMA16(QM, QN, BF)                                                        \
  __builtin_amdgcn_s_setprio(1);                                                  \
  _Pragma("unroll")                                                               \
  for (int mf = 0; mf < 4; ++mf)                                                  \
    _Pragma("unroll")                                                             \
    for (int nf = 0; nf < 2; ++nf)                                                \
      _Pragma("unroll")                                                           \
      for (int ks = 0; ks < 2; ++ks)                                              \
        acc[(QM)*4+mf][(QN)*2+nf] = __builtin_amdgcn_mfma_f32_16x16x32_bf16(      \
            af[mf][ks], BF[nf][ks], acc[(QM)*4+mf][(QN)*2+nf], 0, 0, 0);          \
  __builtin_amdgcn_s_setprio(0);

#define BAR()   asm volatile("" ::: "memory"); __builtin_amdgcn_s_barrier(); asm volatile("" ::: "memory")
#define WAITV(N) asm volatile("s_waitcnt vmcnt(" #N ")" ::: "memory"); __builtin_amdgcn_sched_barrier(0)
#define WAITL(N) asm volatile("s_waitcnt lgkmcnt(" #N ")" ::: "memory"); __builtin_amdgcn_sched_barrier(0)

  stage(0, 0, 0, 0); stage(0, 1, 0, 0); stage(0, 1, 1, 0); stage(0, 0, 1, 0);
  stage(1, 0, 0, 1); stage(1, 1, 0, 1); stage(1, 1, 1, 1);
  WAITV(6);
  BAR();
  readB(0, 0, bl);

#define TILE(KTE, BUF)                                                            \
  {                                                                               \
    const int kt = (KTE);                                                         \
    if (kt >= NT - 2) { WAITV(0); } else { WAITV(8); }                            \
    BAR();                                                                        \
    readA(BUF, 0);                                                                \
    readB(BUF, 1, bh);                                                            \
    if (kt + 1 < NT) stage(BUF ^ 1, 0, 1, kt + 1);                                \
    WAITL(4);                                                                     \
    MFMA16(0, 0, bl);                                                             \
    BAR();                                                                        \
    if (kt + 2 < NT) stage(BUF, 0, 0, kt + 2);                                    \
    WAITL(0);                                                                     \
    MFMA16(0, 1, bh);                                                             \
    if (kt >= NT - 2) { WAITV(0); } else { WAITV(10); }                           \
    BAR();                                                                        \
    readA(BUF, 1);                                                                \
    if (kt + 2 < NT) stage(BUF, 1, 0, kt + 2);                                    \
    WAITL(0);                                                                     \
    MFMA16(1, 0, bl);                                                             \
    if (kt >= NT - 2) { WAITV(0); } else { WAITV(8); }                            \
    BAR();                                                                        \
    if (kt + 1 < NT) readB(BUF ^ 1, 0, bl);                                       \
    if (kt + 2 < NT) stage(BUF, 1, 1, kt + 2);                                    \
    WAITL(4);                                                                     \
    MFMA16(1, 1, bh);                                                             \
  }

  for (int kt2 = 0; kt2 < NT; kt2 += 2) {
    TILE(kt2, 0);
    TILE(kt2 + 1, 1);
  }

#pragma unroll
  for (int qm = 0; qm < 2; ++qm)
#pragma unroll
    for (int mf = 0; mf < 4; ++mf)
#pragma unroll
      for (int qn = 0; qn < 2; ++qn)
#pragma unroll
        for (int nf = 0; nf < 2; ++nf) {
          const int col = n0 + qn * 128 + wn * 32 + nf * 16 + (lane & 15);
          if (col >= N) continue;
          const int row0 = m0 + qm * 128 + wm * 64 + mf * 16 + ((lane >> 4) << 2);
          const f32x4 v = acc[qm * 4 + mf][qn * 2 + nf];
#pragma unroll
          for (int rr2 = 0; rr2 < 4; ++rr2)
            C[(long)(row0 + rr2) * N + col] = v[rr2];
        }
#undef TILE
#undef MFMA16
#undef BAR
#undef WAITV
#undef WAITL
}

// ---------------------------------------------------------------- host
extern "C" void kernel_launch(void* const* d_in, const int* in_sizes, int n_in,
                              void* d_out, int out_size, void* d_ws, size_t ws_size,
                              hipStream_t stream)
{
  (void)in_sizes; (void)n_in; (void)out_size; (void)ws_size;
  const int*   idx   = (const int*)  d_in[0];
  const float* emb   = (const float*)d_in[1];
  const float* W_in  = (const float*)d_in[2];
  const float* convw = (const float*)d_in[3];
  const float* W_xp  = (const float*)d_in[4];
  const float* W_dt  = (const float*)d_in[5];
  const float* b_dt  = (const float*)d_in[6];
  const float* a_log = (const float*)d_in[7];
  const float* d_par = (const float*)d_in[8];
  const float* W_out = (const float*)d_in[9];
  const float* normw = (const float*)d_in[10];
  float* out = (float*)d_out;

  char* ws = (char*)d_ws;
  size_t off = 0;
  auto alloc = [&](size_t bytes) -> void* {
    void* p = ws + off;
    off += (bytes + 255) & ~(size_t)255;
    return p;
  };
  int*   bar    = (int*)  alloc(256);
  u16*   embbf  = (u16*)  alloc((size_t)VPAD * DMODEL * 2);
  u16*   winbf  = (u16*)  alloc((size_t)NLAYER * 2 * DINNER * DMODEL * 2);
  u16*   woutbf = (u16*)  alloc((size_t)NLAYER * DMODEL * DINNER * 2);
  float* xf     = (float*)alloc((size_t)MROWS * DMODEL * 4);
  u16*   xbf    = (u16*)  alloc((size_t)MROWS * DMODEL * 2);
  float* xz0    = (float*)alloc((size_t)MROWS * 2 * DINNER * 4);
  float* xs     = (float*)alloc((size_t)MROWS * DINNER * 4);
  float* dlt    = (float*)alloc((size_t)MROWS * DINNER * 4);
  float* bc     = (float*)alloc((size_t)MROWS * 2 * DSTATE * 4);
  u16*   ybf    = (u16*)  alloc((size_t)MROWS * DINNER * 2);
  u16*   xnbf   = (u16*)  alloc((size_t)MROWS * DMODEL * 2);
  float* part   = (float*)alloc((size_t)4 * MROWS * DMODEL * 4);

  prep_kern<<<2048, 256, 0, stream>>>(emb, W_in, W_out, idx, embbf, winbf, woutbf, xf, xbf, bar);
  mega_kern<<<NBLK, 256, 0, stream>>>(
      convw, W_xp, W_dt, b_dt, a_log, d_par, normw, winbf, woutbf,
      xbf, xf, xz0, xs, dlt, bc, ybf, xnbf, part, bar);
  gemm8_kern<<<4 * (VPAD / 256), 512, 0, stream>>>(
      xnbf, embbf, out, VV, DMODEL, DMODEL, DMODEL);
}

// Round 8
// 2074.564 us; speedup vs baseline: 1.7042x; 1.7042x over previous
//
#include <hip/hip_runtime.h>
#include <cstdint>

#define VV     50257
#define VPAD   50432   // 197 * 256
#define DMODEL 768
#define NLAYER 4
#define DINNER 1536
#define DSTATE 16
#define DCONV  4
#define BATCH  2
#define SEQ    512
#define MROWS  (BATCH*SEQ)   // 1024
#define NBLK   512           // co-residency: launch_bounds(256,2) -> 2 blk/CU by VGPR; 48KB LDS -> 3/CU

typedef unsigned short u16;
typedef __attribute__((ext_vector_type(8))) short bf16x8;
typedef __attribute__((ext_vector_type(4))) float f32x4;

__device__ __forceinline__ u16 f2bf(float f) {
  unsigned u = __float_as_uint(f);
  u += 0x7fffu + ((u >> 16) & 1u);
  return (u16)(u >> 16);
}

__device__ __forceinline__ void async16(const void* g, void* l) {
  auto gp = reinterpret_cast<const __attribute__((address_space(1))) unsigned int*>(
      reinterpret_cast<uintptr_t>(g));
  auto lp = reinterpret_cast<__attribute__((address_space(3))) unsigned int*>(
      reinterpret_cast<uintptr_t>(l));
  __builtin_amdgcn_global_load_lds(gp, lp, 16, 0, 0);
}

// ---------------------------------------------------------------- grid barrier (RELAXED protocol)
// Monotonic count at bar[0]; barrier #idx waits for cnt >= idx*NBLK.
// RELAXED atomics (no per-op L2 inv/wb); exactly one release fence before arrival
// and one acquire fence after exit per block. Periodic refresh + bounded spin failsafe.
__device__ __forceinline__ void gridbar(int* bar, int idx) {
  __syncthreads();
  if (threadIdx.x == 0) {
    __threadfence();   // release: wb so this block's writes reach the coherent point
    __hip_atomic_fetch_add(&bar[0], 1, __ATOMIC_RELAXED, __HIP_MEMORY_SCOPE_AGENT);
    const int target = idx * NBLK;
    int spins = 0;
    while (__hip_atomic_load(&bar[0], __ATOMIC_RELAXED, __HIP_MEMORY_SCOPE_AGENT) < target) {
      __builtin_amdgcn_s_sleep(16);
      ++spins;
      if ((spins & 8191) == 0) __threadfence();   // stale-poll insurance
      if (spins > (1 << 20)) break;               // finite failure instead of hang
    }
    __threadfence();   // acquire: inv so this block sees other XCDs' writes
  }
  __syncthreads();
}

// ---------------------------------------------------------------- fused prep (+ bar zeroing)
__global__ void prep_kern(const float* __restrict__ emb, const float* __restrict__ W_in,
                          const float* __restrict__ W_out, const int* __restrict__ idx,
                          u16* __restrict__ embbf, u16* __restrict__ winbf,
                          u16* __restrict__ woutbf, float* __restrict__ xf,
                          u16* __restrict__ xbf, int* __restrict__ bar) {
  if (blockIdx.x == 0 && threadIdx.x == 0) { bar[0] = 0; bar[1] = 0; }
  const int E4  = VPAD * DMODEL / 4;
  const int W14 = NLAYER * 2 * DINNER * DMODEL / 4;
  const int W24 = NLAYER * DMODEL * DINNER / 4;
  const int X4  = MROWS * DMODEL / 4;
  const int TOT = E4 + W14 + W24 + X4;
  int i = blockIdx.x * blockDim.x + threadIdx.x;
  const int stride = gridDim.x * blockDim.x;
  for (; i < TOT; i += stride) {
    if (i < E4) {
      ushort4 o;
      if (i < VV * DMODEL / 4) {
        float4 v = *(const float4*)(emb + (long)i * 4);
        o.x = f2bf(v.x); o.y = f2bf(v.y); o.z = f2bf(v.z); o.w = f2bf(v.w);
      } else { o.x = 0; o.y = 0; o.z = 0; o.w = 0; }
      *(ushort4*)(embbf + (long)i * 4) = o;
    } else if (i < E4 + W14) {
      const int j = i - E4;
      float4 v = *(const float4*)(W_in + (long)j * 4);
      ushort4 o; o.x = f2bf(v.x); o.y = f2bf(v.y); o.z = f2bf(v.z); o.w = f2bf(v.w);
      *(ushort4*)(winbf + (long)j * 4) = o;
    } else if (i < E4 + W14 + W24) {
      const int j = i - E4 - W14;
      float4 v = *(const float4*)(W_out + (long)j * 4);
      ushort4 o; o.x = f2bf(v.x); o.y = f2bf(v.y); o.z = f2bf(v.z); o.w = f2bf(v.w);
      *(ushort4*)(woutbf + (long)j * 4) = o;
    } else {
      const int j = i - E4 - W14 - W24;
      const int r = j / (DMODEL / 4);
      const int c = (j % (DMODEL / 4)) * 4;
      const int id = idx[r];
      float4 v = *(const float4*)(emb + (long)id * DMODEL + c);
      *(float4*)(xf + (long)r * DMODEL + c) = v;
      ushort4 o; o.x = f2bf(v.x); o.y = f2bf(v.y); o.z = f2bf(v.z); o.w = f2bf(v.w);
      *(ushort4*)(xbf + (long)r * DMODEL + c) = o;
    }
  }
}

// ---------------------------------------------------------------- 128^2 ring-3 GEMM body (device fn)
__device__ __forceinline__ void gemm128(
    const u16* __restrict__ A, const u16* __restrict__ B, float* __restrict__ C,
    int N, int K, int lda, int ldb, int koff, int bx, int by, char* smem)
{
  u16* As = (u16*)smem;                 // 3 * 128*32 u16 = 24576 B
  u16* Bs = (u16*)(smem + 24576);
  const int tid  = threadIdx.x;
  const int wave = tid >> 6;
  const int lane = tid & 63;
  const int wr = wave >> 1, wc = wave & 1;
  const int m0 = bx * 128;
  const int n0 = by * 128;

  const int srow = wave * 32 + (lane >> 2);
  const int sblk = ((lane & 3) ^ ((lane >> 3) & 3)) * 8;

  f32x4 acc[4][4];
#pragma unroll
  for (int i = 0; i < 4; ++i)
#pragma unroll
    for (int j = 0; j < 4; ++j) acc[i][j] = (f32x4){0.f, 0.f, 0.f, 0.f};

  const int arow = wr * 64 + (lane & 15);
  const int brow = wc * 64 + (lane & 15);
  const int sa   = (((lane >> 4) ^ ((lane >> 1) & 3)) << 3);

  const int KT = K / 32;
  auto stage = [&](int kt) {
    const int slot = kt % 3;
    const long kcol = (long)koff + kt * 32;
#pragma unroll
    for (int j = 0; j < 2; ++j) {
      async16(A + (long)(m0 + srow + j * 16) * lda + kcol + sblk,
              As + slot * 128 * 32 + (wave * 32 + j * 16) * 32);
      async16(B + (long)(n0 + srow + j * 16) * ldb + kcol + sblk,
              Bs + slot * 128 * 32 + (wave * 32 + j * 16) * 32);
    }
  };

  asm volatile("s_waitcnt vmcnt(0)" ::: "memory");
  stage(0);
  stage(1);
  for (int t = 0; t < KT; ++t) {
    if (t + 2 < KT) {
      stage(t + 2);
      asm volatile("s_waitcnt vmcnt(8)" ::: "memory");
    } else if (t + 2 == KT) {
      asm volatile("s_waitcnt vmcnt(4)" ::: "memory");
    } else {
      asm volatile("s_waitcnt vmcnt(0)" ::: "memory");
    }
    __builtin_amdgcn_s_barrier();
    asm volatile("" ::: "memory");

    const u16* as = As + (t % 3) * 128 * 32;
    const u16* bs = Bs + (t % 3) * 128 * 32;
    bf16x8 af[4], bv[4];
#pragma unroll
    for (int i = 0; i < 4; ++i) af[i] = *(const bf16x8*)(as + (arow + 16 * i) * 32 + sa);
#pragma unroll
    for (int j = 0; j < 4; ++j) bv[j] = *(const bf16x8*)(bs + (brow + 16 * j) * 32 + sa);

    __builtin_amdgcn_s_setprio(1);
#pragma unroll
    for (int i = 0; i < 4; ++i)
#pragma unroll
      for (int j = 0; j < 4; ++j)
        acc[i][j] = __builtin_amdgcn_mfma_f32_16x16x32_bf16(af[i], bv[j], acc[i][j], 0, 0, 0);
    __builtin_amdgcn_s_setprio(0);

    asm volatile("" ::: "memory");
    __builtin_amdgcn_s_barrier();
    asm volatile("" ::: "memory");
  }

  const int rbase = m0 + wr * 64 + ((lane >> 4) << 2);
  const int cbase = n0 + wc * 64 + (lane & 15);
#pragma unroll
  for (int j = 0; j < 4; ++j) {
    const int col = cbase + j * 16;
#pragma unroll
    for (int i = 0; i < 4; ++i) {
#pragma unroll
      for (int r = 0; r < 4; ++r) {
        const int row = rbase + i * 16 + r;
        C[(long)row * N + col] = acc[i][j][r];
      }
    }
  }
}

// ---------------------------------------------------------------- megakernel: 4 layers + RMS
// Buffer double-duty: phase1 split-K2 second partial in part; after phase3 consumes
// xz, BOTH xz0 and part are dead -> phase4 split-K8 writes 8 partial slices into them.
__global__ __launch_bounds__(256, 2) void mega_kern(
    const float* __restrict__ convw, const float* __restrict__ W_xp,
    const float* __restrict__ W_dt, const float* __restrict__ b_dt,
    const float* __restrict__ a_log, const float* __restrict__ d_par,
    const float* __restrict__ normw,
    const u16* __restrict__ winbf, const u16* __restrict__ woutbf,
    u16* __restrict__ xbf, float* __restrict__ xf,
    float* __restrict__ xz0,
    float* __restrict__ xs, float* __restrict__ dlt, float* __restrict__ bc,
    u16* __restrict__ ybf, u16* __restrict__ xnbf,
    float* __restrict__ part, int* __restrict__ bar)
{
  __shared__ __align__(16) char smem[49152];
  const int bid = blockIdx.x;
  const int tid = threadIdx.x;
  int bcount = 0;

#pragma unroll 1
  for (int l = 0; l < NLAYER; ++l) {
    // ===== phase 1: xz = x @ W_in^T, split-K x2 (384 tasks); ks1 -> part =====
    if (bid < 384) {
      const int ks = bid & 1, t = bid >> 1;          // t: 0..191
      gemm128(xbf, winbf + (size_t)l * 2 * DINNER * DMODEL, ks ? part : xz0,
              2 * DINNER, DMODEL / 2, DMODEL, DMODEL, ks * (DMODEL / 2),
              t & 7, t >> 3, smem);
    }
    gridbar(bar, ++bcount);

    // ===== phase 2: conv + SiLU + xproj + delta (2 rows/block) =====
    {
      float* sx  = (float*)smem;
      float* sxp = (float*)(smem + DINNER * 4);
      const float* cw  = convw + (size_t)l * DINNER * DCONV;
      const float* Wx  = W_xp + (size_t)l * (2 * DSTATE + 1) * DINNER;
      const float* wdt = W_dt + (size_t)l * DINNER;
      const float* bdt = b_dt + (size_t)l * DINNER;
#pragma unroll 1
      for (int rr = 0; rr < 2; ++rr) {
        const int row = bid * 2 + rr;
        const int trow = row & (SEQ - 1);
        for (int c = tid; c < DINNER; c += 256) {
          const float* w = cw + c * DCONV;
          float a = 0.f;
#pragma unroll
          for (int k = 0; k < DCONV; ++k) {
            const int tt = trow - (DCONV - 1) + k;
            if (tt >= 0) {
              const long ix = (long)(row - (DCONV - 1) + k) * (2 * DINNER) + c;
              a += w[k] * (xz0[ix] + part[ix]);
            }
          }
          const float s = a / (1.f + __expf(-a));
          sx[c] = s;
          xs[(long)row * DINNER + c] = s;
        }
        __syncthreads();
        const int wv = tid >> 6, lane = tid & 63;
        for (int e = wv; e < 2 * DSTATE + 1; e += 4) {
          const float* We = Wx + (long)e * DINNER;
          float p = 0.f;
          for (int d = lane; d < DINNER; d += 64) p += sx[d] * We[d];
#pragma unroll
          for (int off2 = 32; off2; off2 >>= 1) p += __shfl_xor(p, off2, 64);
          if (lane == 0) sxp[e] = p;
        }
        __syncthreads();
        const float dtr = sxp[0];
        for (int d = tid; d < DINNER; d += 256) {
          float v = dtr * wdt[d] + bdt[d];
          float sp = (v > 15.f) ? v : log1pf(__expf(v));
          dlt[(long)row * DINNER + d] = sp;
        }
        if (tid < 2 * DSTATE) bc[(long)row * (2 * DSTATE) + tid] = sxp[1 + tid];
        __syncthreads();
      }
    }
    gridbar(bar, ++bcount);

    // ===== phase 3: chunked scan + gate (384 tasks, 32 chunks x 16 steps) =====
    if (bid < 384) {
      float (*sh_h)[8][DSTATE] = (float(*)[8][DSTATE])smem;       // 16 KB
      float (*sh_s)[8]         = (float(*)[8])(smem + 16384);
      const float* alog = a_log + (size_t)l * DINNER * DSTATE;
      const float* dpar = d_par + (size_t)l * DINNER;
      const int ch = tid & 7, chunk = tid >> 3;       // chunk 0..31
      const int ch_abs = bid * 8 + ch;
      const int b = ch_abs / DINNER, d = ch_abs % DINNER;
      float An[DSTATE];
#pragma unroll
      for (int n = 0; n < DSTATE; ++n) An[n] = -__expf(alog[(long)d * DSTATE + n]);
      const int r0 = b * SEQ + chunk * 16;

      float h[DSTATE];
#pragma unroll
      for (int n = 0; n < DSTATE; ++n) h[n] = 0.f;
      float ssum = 0.f;
      for (int s = 0; s < 16; ++s) {
        const int row = r0 + s;
        const float dl = dlt[(long)row * DINNER + d];
        const float xv = xs[(long)row * DINNER + d];
        const float dx = dl * xv;
        const float4* bp = (const float4*)(bc + (long)row * (2 * DSTATE));
        float Bv[DSTATE];
        *(float4*)&Bv[0] = bp[0]; *(float4*)&Bv[4] = bp[1];
        *(float4*)&Bv[8] = bp[2]; *(float4*)&Bv[12] = bp[3];
        ssum += dl;
#pragma unroll
        for (int n = 0; n < DSTATE; ++n) h[n] = __expf(dl * An[n]) * h[n] + dx * Bv[n];
      }
#pragma unroll
      for (int n = 0; n < DSTATE; ++n) sh_h[chunk][ch][n] = h[n];
      sh_s[chunk][ch] = ssum;
      __syncthreads();

      if (tid < 128) {
        const int n2 = tid & 15, ch2 = tid >> 4;
        const int d2 = (bid * 8 + ch2) % DINNER;
        const float A2 = -__expf(alog[(long)d2 * DSTATE + n2]);
        float carry = 0.f;
        for (int c = 0; c < 32; ++c) {
          const float hl = sh_h[c][ch2][n2];
          sh_h[c][ch2][n2] = carry;
          carry = __expf(A2 * sh_s[c][ch2]) * carry + hl;
        }
      }
      __syncthreads();

#pragma unroll
      for (int n = 0; n < DSTATE; ++n) h[n] = sh_h[chunk][ch][n];
      const float dp = dpar[d];
      for (int s = 0; s < 16; ++s) {
        const int row = r0 + s;
        const float dl = dlt[(long)row * DINNER + d];
        const float xv = xs[(long)row * DINNER + d];
        const float dx = dl * xv;
        const float4* bp = (const float4*)(bc + (long)row * (2 * DSTATE));
        float Bv[DSTATE], Cv[DSTATE];
        *(float4*)&Bv[0] = bp[0]; *(float4*)&Bv[4] = bp[1];
        *(float4*)&Bv[8] = bp[2]; *(float4*)&Bv[12] = bp[3];
        *(float4*)&Cv[0] = bp[4]; *(float4*)&Cv[4] = bp[5];
        *(float4*)&Cv[8] = bp[6]; *(float4*)&Cv[12] = bp[7];
        float y = 0.f;
#pragma unroll
        for (int n = 0; n < DSTATE; ++n) {
          const float hn = __expf(dl * An[n]) * h[n] + dx * Bv[n];
          h[n] = hn;
          y += Cv[n] * hn;
        }
        y += dp * xv;
        const long zix = (long)row * (2 * DINNER) + DINNER + d;
        const float zz = xz0[zix] + part[zix];
        const float o = y * (zz / (1.f + __expf(-zz)));
        ybf[(long)row * DINNER + d] = f2bf(o);
      }
    }
    gridbar(bar, ++bcount);

    // ===== phase 4: out-proj split-K x8 (384 tasks) -> 8 slices in xz0|part =====
    if (bid < 384) {
      const int ks = bid & 7, tile = bid >> 3;        // tile: 0..47
      float* dst = (ks < 4 ? xz0 : part) + (size_t)(ks & 3) * MROWS * DMODEL;
      gemm128(ybf, woutbf + (size_t)l * DMODEL * DINNER, dst,
              DMODEL, DINNER / 8, DINNER, DINNER, ks * (DINNER / 8),
              tile & 7, tile >> 3, smem);
    }
    gridbar(bar, ++bcount);

    // ===== phase 5: reduce 8 partials + residual (skip on last layer) =====
    if (l < NLAYER - 1) {
      const int stride4 = MROWS * DMODEL / 4;
      for (int i = bid * 256 + tid; i < stride4; i += NBLK * 256) {
        float4 s = ((const float4*)xf)[i];
#pragma unroll
        for (int k = 0; k < 4; ++k) {
          float4 p = ((const float4*)xz0)[i + k * stride4];
          s.x += p.x; s.y += p.y; s.z += p.z; s.w += p.w;
        }
#pragma unroll
        for (int k = 0; k < 4; ++k) {
          float4 p = ((const float4*)part)[i + k * stride4];
          s.x += p.x; s.y += p.y; s.z += p.z; s.w += p.w;
        }
        ((float4*)xf)[i] = s;
        ushort4 o; o.x = f2bf(s.x); o.y = f2bf(s.y); o.z = f2bf(s.z); o.w = f2bf(s.w);
        ((ushort4*)xbf)[i] = o;
      }
      gridbar(bar, ++bcount);
    }
  }

  // ===== final: 8-partial reduce + residual + RMSNorm -> bf16 (2 rows/block) =====
  {
    float* red = (float*)smem;
    const int S = MROWS * DMODEL;
#pragma unroll 1
    for (int rr = 0; rr < 2; ++rr) {
      const int row = bid * 2 + rr;
      float v[3];
      float p = 0.f;
#pragma unroll
      for (int k = 0; k < 3; ++k) {
        const int i = row * DMODEL + tid + k * 256;
        float x = xf[i];
#pragma unroll
        for (int q2 = 0; q2 < 4; ++q2) x += xz0[i + q2 * S];
#pragma unroll
        for (int q2 = 0; q2 < 4; ++q2) x += part[i + q2 * S];
        v[k] = x;
        p += x * x;
      }
#pragma unroll
      for (int off2 = 32; off2; off2 >>= 1) p += __shfl_xor(p, off2, 64);
      const int wv = tid >> 6, lane = tid & 63;
      if (lane == 0) red[wv] = p;
      __syncthreads();
      if (tid == 0) {
        float tsum = red[0] + red[1] + red[2] + red[3];
        red[4] = rsqrtf(tsum / (float)DMODEL + 1e-5f);
      }
      __syncthreads();
      const float r = red[4];
#pragma unroll
      for (int k = 0; k < 3; ++k) {
        const int dd = tid + k * 256;
        xnbf[(long)row * DMODEL + dd] = f2bf(v[k] * r * normw[dd]);
      }
      __syncthreads();
    }
  }
}

// ---------------------------------------------------------------- 256^2 4-phase pipelined GEMM (logits, unchanged)
__global__ __launch_bounds__(512, 2) void gemm8_kern(
    const u16* __restrict__ A, const u16* __restrict__ B,
    float* __restrict__ C, int N, int K, int lda, int ldb)
{
  __shared__ u16 lds[2][2][256 * 64];
  const int tid = threadIdx.x;
  const int wave = tid >> 6;
  const int lane = tid & 63;
  const int wm = wave >> 2, wn = wave & 3;

  const int nwg = gridDim.x;
  const int q = nwg >> 3, r = nwg & 7;
  const int xcd = blockIdx.x & 7;
  const int t = (xcd < r ? xcd * (q + 1) : r * (q + 1) + (xcd - r) * q) + (blockIdx.x >> 3);
  const int m0 = (t & 3) * 256;
  const int n0 = (t >> 2) * 256;

  const int NT = K / 64;

  const int sblk = (((lane & 7) ^ (lane >> 3)) << 3);
  auto stage = [&](int buf, int ab, int half, int kt) {
    const u16* Mat = ab ? B : A;
    const int ld = ab ? ldb : lda;
    const int tb = ab ? n0 : m0;
#pragma unroll
    for (int j = 0; j < 2; ++j) {
      const int rloc = half * 128 + j * 64 + wave * 8;
      async16(Mat + (long)(tb + rloc + (lane >> 3)) * ld + kt * 64 + sblk,
              (char*)&lds[buf][ab][0] + (rloc << 7));
    }
  };

  bf16x8 af[4][2], bl[2][2], bh[2][2];
  const int aq = lane >> 4;
  auto readA = [&](int buf, int half) {
#pragma unroll
    for (int mf = 0; mf < 4; ++mf) {
      const int rr = half * 128 + wm * 64 + mf * 16 + (lane & 15);
#pragma unroll
      for (int ks = 0; ks < 2; ++ks) {
        const int q2 = ks * 4 + aq;
        af[mf][ks] = *(const bf16x8*)(&lds[buf][0][0] + rr * 64 + ((q2 ^ (rr & 7)) << 3));
      }
    }
  };
  auto readB = [&](int buf, int half, bf16x8 (&bf)[2][2]) {
#pragma unroll
    for (int nf = 0; nf < 2; ++nf) {
      const int rr = half * 128 + wn * 32 + nf * 16 + (lane & 15);
#pragma unroll
      for (int ks = 0; ks < 2; ++ks) {
        const int q2 = ks * 4 + aq;
        bf[nf][ks] = *(const bf16x8*)(&lds[buf][1][0] + rr * 64 + ((q2 ^ (rr & 7)) << 3));
      }
    }
  };

  f32x4 acc[8][4];
#pragma unroll
  for (int i = 0; i < 8; ++i)
#pragma unroll
    for (int j = 0; j < 4; ++j) acc[i][j] = (f32x4){0.f, 0.f, 0.f, 0.f};

#define MFMA16(QM, QN, BF)                                                        \
  __builtin_amdgcn_s_setprio(1);                                                  \
  _Pragma("unroll")                                                               \
  for (int mf = 0; mf < 4; ++mf)                                                  \
    _Pragma("unroll")                                                             \
    for (int nf = 0; nf < 2; ++nf)                                                \
      _Pragma("unroll")                                                           \
      for (int ks = 0; ks < 2; ++ks)                                              \
        acc[(QM)*4+mf][(QN)*2+nf] = __builtin_amdgcn_mfma_f32_16x16x32_bf16(      \
            af[mf][ks], BF[nf][ks], acc[(QM)*4+mf][(QN)*2+nf], 0, 0, 0);          \
  __builtin_amdgcn_s_setprio(0);

#define BAR()   asm volatile("" ::: "memory"); __builtin_amdgcn_s_barrier(); asm volatile("" ::: "memory")
#define WAITV(N) asm volatile("s_waitcnt vmcnt(" #N ")" ::: "memory"); __builtin_amdgcn_sched_barrier(0)
#define WAITL(N) asm volatile("s_waitcnt lgkmcnt(" #N ")" ::: "memory"); __builtin_amdgcn_sched_barrier(0)

  stage(0, 0, 0, 0); stage(0, 1, 0, 0); stage(0, 1, 1, 0); stage(0, 0, 1, 0);
  stage(1, 0, 0, 1); stage(1, 1, 0, 1); stage(1, 1, 1, 1);
  WAITV(6);
  BAR();
  readB(0, 0, bl);

#define TILE(KTE, BUF)                                                            \
  {                                                                               \
    const int kt = (KTE);                                                         \
    if (kt >= NT - 2) { WAITV(0); } else { WAITV(8); }                            \
    BAR();                                                                        \
    readA(BUF, 0);                                                                \
    readB(BUF, 1, bh);                                                            \
    if (kt + 1 < NT) stage(BUF ^ 1, 0, 1, kt + 1);                                \
    WAITL(4);                                                                     \
    MFMA16(0, 0, bl);                                                             \
    BAR();                                                                        \
    if (kt + 2 < NT) stage(BUF, 0, 0, kt + 2);                                    \
    WAITL(0);                                                                     \
    MFMA16(0, 1, bh);                                                             \
    if (kt >= NT - 2) { WAITV(0); } else { WAITV(10); }                           \
    BAR();                                                                        \
    readA(BUF, 1);                                                                \
    if (kt + 2 < NT) stage(BUF, 1, 0, kt + 2);                                    \
    WAITL(0);                                                                     \
    MFMA16(1, 0, bl);                                                             \
    if (kt >= NT - 2) { WAITV(0); } else { WAITV(8); }                            \
    BAR();                                                                        \
    if (kt + 1 < NT) readB(BUF ^ 1, 0, bl);                                       \
    if (kt + 2 < NT) stage(BUF, 1, 1, kt + 2);                                    \
    WAITL(4);                                                                     \
    MFMA16(1, 1, bh);                                                             \
  }

  for (int kt2 = 0; kt2 < NT; kt2 += 2) {
    TILE(kt2, 0);
    TILE(kt2 + 1, 1);
  }

#pragma unroll
  for (int qm = 0; qm < 2; ++qm)
#pragma unroll
    for (int mf = 0; mf < 4; ++mf)
#pragma unroll
      for (int qn = 0; qn < 2; ++qn)
#pragma unroll
        for (int nf = 0; nf < 2; ++nf) {
          const int col = n0 + qn * 128 + wn * 32 + nf * 16 + (lane & 15);
          if (col >= N) continue;
          const int row0 = m0 + qm * 128 + wm * 64 + mf * 16 + ((lane >> 4) << 2);
          const f32x4 v = acc[qm * 4 + mf][qn * 2 + nf];
#pragma unroll
          for (int rr2 = 0; rr2 < 4; ++rr2)
            C[(long)(row0 + rr2) * N + col] = v[rr2];
        }
#undef TILE
#undef MFMA16
#undef BAR
#undef WAITV
#undef WAITL
}

// ---------------------------------------------------------------- host
extern "C" void kernel_launch(void* const* d_in, const int* in_sizes, int n_in,
                              void* d_out, int out_size, void* d_ws, size_t ws_size,
                              hipStream_t stream)
{
  (void)in_sizes; (void)n_in; (void)out_size; (void)ws_size;
  const int*   idx   = (const int*)  d_in[0];
  const float* emb   = (const float*)d_in[1];
  const float* W_in  = (const float*)d_in[2];
  const float* convw = (const float*)d_in[3];
  const float* W_xp  = (const float*)d_in[4];
  const float* W_dt  = (const float*)d_in[5];
  const float* b_dt  = (const float*)d_in[6];
  const float* a_log = (const float*)d_in[7];
  const float* d_par = (const float*)d_in[8];
  const float* W_out = (const float*)d_in[9];
  const float* normw = (const float*)d_in[10];
  float* out = (float*)d_out;

  char* ws = (char*)d_ws;
  size_t off = 0;
  auto alloc = [&](size_t bytes) -> void* {
    void* p = ws + off;
    off += (bytes + 255) & ~(size_t)255;
    return p;
  };
  int*   bar    = (int*)  alloc(256);
  u16*   embbf  = (u16*)  alloc((size_t)VPAD * DMODEL * 2);
  u16*   winbf  = (u16*)  alloc((size_t)NLAYER * 2 * DINNER * DMODEL * 2);
  u16*   woutbf = (u16*)  alloc((size_t)NLAYER * DMODEL * DINNER * 2);
  float* xf     = (float*)alloc((size_t)MROWS * DMODEL * 4);
  u16*   xbf    = (u16*)  alloc((size_t)MROWS * DMODEL * 2);
  float* xz0    = (float*)alloc((size_t)MROWS * 2 * DINNER * 4);
  float* xs     = (float*)alloc((size_t)MROWS * DINNER * 4);
  float* dlt    = (float*)alloc((size_t)MROWS * DINNER * 4);
  float* bc     = (float*)alloc((size_t)MROWS * 2 * DSTATE * 4);
  u16*   ybf    = (u16*)  alloc((size_t)MROWS * DINNER * 2);
  u16*   xnbf   = (u16*)  alloc((size_t)MROWS * DMODEL * 2);
  float* part   = (float*)alloc((size_t)4 * MROWS * DMODEL * 4);

  prep_kern<<<2048, 256, 0, stream>>>(emb, W_in, W_out, idx, embbf, winbf, woutbf, xf, xbf, bar);
  mega_kern<<<NBLK, 256, 0, stream>>>(
      convw, W_xp, W_dt, b_dt, a_log, d_par, normw, winbf, woutbf,
      xbf, xf, xz0, xs, dlt, bc, ybf, xnbf, part, bar);
  gemm8_kern<<<4 * (VPAD / 256), 512, 0, stream>>>(
      xnbf, embbf, out, VV, DMODEL, DMODEL, DMODEL);
}

// Round 9
// 1721.079 us; speedup vs baseline: 2.0542x; 1.2054x over previous
//
#include <hip/hip_runtime.h>
#include <cstdint>

#define VV     50257
#define VPAD   50432   // 197 * 256
#define DMODEL 768
#define NLAYER 4
#define DINNER 1536
#define DSTATE 16
#define DCONV  4
#define BATCH  2
#define SEQ    512
#define MROWS  (BATCH*SEQ)   // 1024
#define NBLK   512           // co-residency: launch_bounds(256,2) -> >=2 blk/CU by VGPR; 48KB LDS -> 3/CU
#define NGRP   8
#define GRPSZ  (NBLK/NGRP)   // 64

typedef unsigned short u16;
typedef __attribute__((ext_vector_type(8))) short bf16x8;
typedef __attribute__((ext_vector_type(4))) float f32x4;

__device__ __forceinline__ u16 f2bf(float f) {
  unsigned u = __float_as_uint(f);
  u += 0x7fffu + ((u >> 16) & 1u);
  return (u16)(u >> 16);
}

__device__ __forceinline__ void async16(const void* g, void* l) {
  auto gp = reinterpret_cast<const __attribute__((address_space(1))) unsigned int*>(
      reinterpret_cast<uintptr_t>(g));
  auto lp = reinterpret_cast<__attribute__((address_space(3))) unsigned int*>(
      reinterpret_cast<uintptr_t>(l));
  __builtin_amdgcn_global_load_lds(gp, lp, 16, 0, 0);
}

// ---------------------------------------------------------------- two-level grid barrier
// Monotonic counters, RELAXED atomics. Group g = bid&7 (64 blocks/group by construction).
// bar[32*g]: group arrival cnt; bar[32*g+16]: group release gen; bar[512]: global cnt.
// Only 8 leader blocks touch the global line; members poll their group line (64 readers).
// One release fence before arrival, one acquire fence after exit. Bounded spins -> finite failure.
__device__ __forceinline__ void gridbar(int* bar, int idx) {
  __syncthreads();
  if (threadIdx.x == 0) {
    const int g = blockIdx.x & 7;
    __threadfence();   // release: this block's writes reach the coherent point
    __hip_atomic_fetch_add(&bar[32 * g], 1, __ATOMIC_RELAXED, __HIP_MEMORY_SCOPE_AGENT);
    if (blockIdx.x < NGRP) {             // leader of group g (bid==g)
      int spins = 0;
      while (__hip_atomic_load(&bar[32 * g], __ATOMIC_RELAXED, __HIP_MEMORY_SCOPE_AGENT) < idx * GRPSZ) {
        __builtin_amdgcn_s_sleep(2);
        if (++spins > (1 << 22)) break;
      }
      __hip_atomic_fetch_add(&bar[512], 1, __ATOMIC_RELAXED, __HIP_MEMORY_SCOPE_AGENT);
      spins = 0;
      while (__hip_atomic_load(&bar[512], __ATOMIC_RELAXED, __HIP_MEMORY_SCOPE_AGENT) < idx * NGRP) {
        __builtin_amdgcn_s_sleep(2);
        if (++spins > (1 << 22)) break;
      }
      __hip_atomic_store(&bar[32 * g + 16], idx, __ATOMIC_RELAXED, __HIP_MEMORY_SCOPE_AGENT);
    } else {
      int spins = 0;
      while (__hip_atomic_load(&bar[32 * g + 16], __ATOMIC_RELAXED, __HIP_MEMORY_SCOPE_AGENT) < idx) {
        __builtin_amdgcn_s_sleep(4);
        if (++spins > (1 << 22)) break;
      }
    }
    __threadfence();   // acquire: see other XCDs' writes
  }
  __syncthreads();
}

// ---------------------------------------------------------------- 128^2 ring-3 GEMM body
// ATOMIC: C-write becomes relaxed atomicAdd (for split-K accumulate into live buffer).
template<bool ATOMIC>
__device__ __forceinline__ void gemm128(
    const u16* __restrict__ A, const u16* __restrict__ B, float* __restrict__ C,
    int N, int K, int lda, int ldb, int koff, int bx, int by, char* smem)
{
  u16* As = (u16*)smem;                 // 3 * 128*32 u16 = 24576 B
  u16* Bs = (u16*)(smem + 24576);
  const int tid  = threadIdx.x;
  const int wave = tid >> 6;
  const int lane = tid & 63;
  const int wr = wave >> 1, wc = wave & 1;
  const int m0 = bx * 128;
  const int n0 = by * 128;

  const int srow = wave * 32 + (lane >> 2);
  const int sblk = ((lane & 3) ^ ((lane >> 3) & 3)) * 8;

  f32x4 acc[4][4];
#pragma unroll
  for (int i = 0; i < 4; ++i)
#pragma unroll
    for (int j = 0; j < 4; ++j) acc[i][j] = (f32x4){0.f, 0.f, 0.f, 0.f};

  const int arow = wr * 64 + (lane & 15);
  const int brow = wc * 64 + (lane & 15);
  const int sa   = (((lane >> 4) ^ ((lane >> 1) & 3)) << 3);

  const int KT = K / 32;
  auto stage = [&](int kt) {
    const int slot = kt % 3;
    const long kcol = (long)koff + kt * 32;
#pragma unroll
    for (int j = 0; j < 2; ++j) {
      async16(A + (long)(m0 + srow + j * 16) * lda + kcol + sblk,
              As + slot * 128 * 32 + (wave * 32 + j * 16) * 32);
      async16(B + (long)(n0 + srow + j * 16) * ldb + kcol + sblk,
              Bs + slot * 128 * 32 + (wave * 32 + j * 16) * 32);
    }
  };

  asm volatile("s_waitcnt vmcnt(0)" ::: "memory");
  stage(0);
  stage(1);
  for (int t = 0; t < KT; ++t) {
    if (t + 2 < KT) {
      stage(t + 2);
      asm volatile("s_waitcnt vmcnt(8)" ::: "memory");
    } else if (t + 2 == KT) {
      asm volatile("s_waitcnt vmcnt(4)" ::: "memory");
    } else {
      asm volatile("s_waitcnt vmcnt(0)" ::: "memory");
    }
    __builtin_amdgcn_s_barrier();
    asm volatile("" ::: "memory");

    const u16* as = As + (t % 3) * 128 * 32;
    const u16* bs = Bs + (t % 3) * 128 * 32;
    bf16x8 af[4], bv[4];
#pragma unroll
    for (int i = 0; i < 4; ++i) af[i] = *(const bf16x8*)(as + (arow + 16 * i) * 32 + sa);
#pragma unroll
    for (int j = 0; j < 4; ++j) bv[j] = *(const bf16x8*)(bs + (brow + 16 * j) * 32 + sa);

    __builtin_amdgcn_s_setprio(1);
#pragma unroll
    for (int i = 0; i < 4; ++i)
#pragma unroll
      for (int j = 0; j < 4; ++j)
        acc[i][j] = __builtin_amdgcn_mfma_f32_16x16x32_bf16(af[i], bv[j], acc[i][j], 0, 0, 0);
    __builtin_amdgcn_s_setprio(0);

    asm volatile("" ::: "memory");
    __builtin_amdgcn_s_barrier();
    asm volatile("" ::: "memory");
  }

  const int rbase = m0 + wr * 64 + ((lane >> 4) << 2);
  const int cbase = n0 + wc * 64 + (lane & 15);
#pragma unroll
  for (int j = 0; j < 4; ++j) {
    const int col = cbase + j * 16;
#pragma unroll
    for (int i = 0; i < 4; ++i) {
#pragma unroll
      for (int r = 0; r < 4; ++r) {
        const int row = rbase + i * 16 + r;
        const long off = (long)row * N + col;
        if (ATOMIC) {
          __hip_atomic_fetch_add(&C[off], acc[i][j][r], __ATOMIC_RELAXED,
                                 __HIP_MEMORY_SCOPE_AGENT);
        } else {
          C[off] = acc[i][j][r];
        }
      }
    }
  }
}

// ---------------------------------------------------------------- megakernel: prep + 4 layers + RMS
__global__ __launch_bounds__(256, 2) void mega_kern(
    const float* __restrict__ emb, const float* __restrict__ W_in,
    const float* __restrict__ W_out, const int* __restrict__ idx,
    const float* __restrict__ convw, const float* __restrict__ W_xp,
    const float* __restrict__ W_dt, const float* __restrict__ b_dt,
    const float* __restrict__ a_log, const float* __restrict__ d_par,
    const float* __restrict__ normw,
    u16* __restrict__ embbf, u16* __restrict__ winbf, u16* __restrict__ woutbf,
    u16* __restrict__ xbf, float* __restrict__ xf,
    float* __restrict__ xz0,
    float* __restrict__ xs, float* __restrict__ dlt, float* __restrict__ bc,
    u16* __restrict__ ybf, u16* __restrict__ xnbf,
    float* __restrict__ part, int* __restrict__ bar)
{
  __shared__ __align__(16) char smem[49152];
  const int bid = blockIdx.x;
  const int tid = threadIdx.x;
  int bcount = 0;

  // ===== phase 0: prep (cvt emb/W_in/W_out -> bf16; embed gather -> xf, xbf) =====
  {
    const int E4  = VPAD * DMODEL / 4;
    const int W14 = NLAYER * 2 * DINNER * DMODEL / 4;
    const int W24 = NLAYER * DMODEL * DINNER / 4;
    const int X4  = MROWS * DMODEL / 4;
    const int TOT = E4 + W14 + W24 + X4;
    for (int i = bid * 256 + tid; i < TOT; i += NBLK * 256) {
      if (i < E4) {
        ushort4 o;
        if (i < VV * DMODEL / 4) {
          float4 v = *(const float4*)(emb + (long)i * 4);
          o.x = f2bf(v.x); o.y = f2bf(v.y); o.z = f2bf(v.z); o.w = f2bf(v.w);
        } else { o.x = 0; o.y = 0; o.z = 0; o.w = 0; }
        *(ushort4*)(embbf + (long)i * 4) = o;
      } else if (i < E4 + W14) {
        const int j = i - E4;
        float4 v = *(const float4*)(W_in + (long)j * 4);
        ushort4 o; o.x = f2bf(v.x); o.y = f2bf(v.y); o.z = f2bf(v.z); o.w = f2bf(v.w);
        *(ushort4*)(winbf + (long)j * 4) = o;
      } else if (i < E4 + W14 + W24) {
        const int j = i - E4 - W14;
        float4 v = *(const float4*)(W_out + (long)j * 4);
        ushort4 o; o.x = f2bf(v.x); o.y = f2bf(v.y); o.z = f2bf(v.z); o.w = f2bf(v.w);
        *(ushort4*)(woutbf + (long)j * 4) = o;
      } else {
        const int j = i - E4 - W14 - W24;
        const int r = j / (DMODEL / 4);
        const int c = (j % (DMODEL / 4)) * 4;
        const int id = idx[r];
        float4 v = *(const float4*)(emb + (long)id * DMODEL + c);
        *(float4*)(xf + (long)r * DMODEL + c) = v;
        ushort4 o; o.x = f2bf(v.x); o.y = f2bf(v.y); o.z = f2bf(v.z); o.w = f2bf(v.w);
        *(ushort4*)(xbf + (long)r * DMODEL + c) = o;
      }
    }
  }
  gridbar(bar, ++bcount);

#pragma unroll 1
  for (int l = 0; l < NLAYER; ++l) {
    // ===== phase 1: xz = x @ W_in^T, split-K x2 (384 tasks); ks0->xz0, ks1->part =====
    if (bid < 384) {
      const int ks = bid & 1, t = bid >> 1;          // t: 0..191
      gemm128<false>(xbf, winbf + (size_t)l * 2 * DINNER * DMODEL, ks ? part : xz0,
                     2 * DINNER, DMODEL / 2, DMODEL, DMODEL, ks * (DMODEL / 2),
                     t & 7, t >> 3, smem);
    }
    gridbar(bar, ++bcount);

    // ===== phase 2: conv + SiLU + xproj + delta (2 rows/block) =====
    {
      float* sx  = (float*)smem;
      float* sxp = (float*)(smem + DINNER * 4);
      const float* cw  = convw + (size_t)l * DINNER * DCONV;
      const float* Wx  = W_xp + (size_t)l * (2 * DSTATE + 1) * DINNER;
      const float* wdt = W_dt + (size_t)l * DINNER;
      const float* bdt = b_dt + (size_t)l * DINNER;
#pragma unroll 1
      for (int rr = 0; rr < 2; ++rr) {
        const int row = bid * 2 + rr;
        const int trow = row & (SEQ - 1);
        for (int c = tid; c < DINNER; c += 256) {
          const float* w = cw + c * DCONV;
          float a = 0.f;
#pragma unroll
          for (int k = 0; k < DCONV; ++k) {
            const int tt = trow - (DCONV - 1) + k;
            if (tt >= 0) {
              const long ix = (long)(row - (DCONV - 1) + k) * (2 * DINNER) + c;
              a += w[k] * (xz0[ix] + part[ix]);
            }
          }
          const float s = a / (1.f + __expf(-a));
          sx[c] = s;
          xs[(long)row * DINNER + c] = s;
        }
        __syncthreads();
        const int wv = tid >> 6, lane = tid & 63;
        for (int e = wv; e < 2 * DSTATE + 1; e += 4) {
          const float* We = Wx + (long)e * DINNER;
          float p = 0.f;
          for (int d = lane; d < DINNER; d += 64) p += sx[d] * We[d];
#pragma unroll
          for (int off2 = 32; off2; off2 >>= 1) p += __shfl_xor(p, off2, 64);
          if (lane == 0) sxp[e] = p;
        }
        __syncthreads();
        const float dtr = sxp[0];
        for (int d = tid; d < DINNER; d += 256) {
          float v = dtr * wdt[d] + bdt[d];
          float sp = (v > 15.f) ? v : log1pf(__expf(v));
          dlt[(long)row * DINNER + d] = sp;
        }
        if (tid < 2 * DSTATE) bc[(long)row * (2 * DSTATE) + tid] = sxp[1 + tid];
        __syncthreads();
      }
    }
    gridbar(bar, ++bcount);

    // ===== phase 3: chunked scan + gate (384 tasks, 32 chunks x 16 steps) =====
    if (bid < 384) {
      float (*sh_h)[8][DSTATE] = (float(*)[8][DSTATE])smem;       // 16 KB
      float (*sh_s)[8]         = (float(*)[8])(smem + 16384);
      const float* alog = a_log + (size_t)l * DINNER * DSTATE;
      const float* dpar = d_par + (size_t)l * DINNER;
      const int ch = tid & 7, chunk = tid >> 3;       // chunk 0..31
      const int ch_abs = bid * 8 + ch;
      const int b = ch_abs / DINNER, d = ch_abs % DINNER;
      float An[DSTATE];
#pragma unroll
      for (int n = 0; n < DSTATE; ++n) An[n] = -__expf(alog[(long)d * DSTATE + n]);
      const int r0 = b * SEQ + chunk * 16;

      float h[DSTATE];
#pragma unroll
      for (int n = 0; n < DSTATE; ++n) h[n] = 0.f;
      float ssum = 0.f;
      for (int s = 0; s < 16; ++s) {
        const int row = r0 + s;
        const float dl = dlt[(long)row * DINNER + d];
        const float xv = xs[(long)row * DINNER + d];
        const float dx = dl * xv;
        const float4* bp = (const float4*)(bc + (long)row * (2 * DSTATE));
        float Bv[DSTATE];
        *(float4*)&Bv[0] = bp[0]; *(float4*)&Bv[4] = bp[1];
        *(float4*)&Bv[8] = bp[2]; *(float4*)&Bv[12] = bp[3];
        ssum += dl;
#pragma unroll
        for (int n = 0; n < DSTATE; ++n) h[n] = __expf(dl * An[n]) * h[n] + dx * Bv[n];
      }
#pragma unroll
      for (int n = 0; n < DSTATE; ++n) sh_h[chunk][ch][n] = h[n];
      sh_s[chunk][ch] = ssum;
      __syncthreads();

      if (tid < 128) {
        const int n2 = tid & 15, ch2 = tid >> 4;
        const int d2 = (bid * 8 + ch2) % DINNER;
        const float A2 = -__expf(alog[(long)d2 * DSTATE + n2]);
        float carry = 0.f;
        for (int c = 0; c < 32; ++c) {
          const float hl = sh_h[c][ch2][n2];
          sh_h[c][ch2][n2] = carry;
          carry = __expf(A2 * sh_s[c][ch2]) * carry + hl;
        }
      }
      __syncthreads();

#pragma unroll
      for (int n = 0; n < DSTATE; ++n) h[n] = sh_h[chunk][ch][n];
      const float dp = dpar[d];
      for (int s = 0; s < 16; ++s) {
        const int row = r0 + s;
        const float dl = dlt[(long)row * DINNER + d];
        const float xv = xs[(long)row * DINNER + d];
        const float dx = dl * xv;
        const float4* bp = (const float4*)(bc + (long)row * (2 * DSTATE));
        float Bv[DSTATE], Cv[DSTATE];
        *(float4*)&Bv[0] = bp[0]; *(float4*)&Bv[4] = bp[1];
        *(float4*)&Bv[8] = bp[2]; *(float4*)&Bv[12] = bp[3];
        *(float4*)&Cv[0] = bp[4]; *(float4*)&Cv[4] = bp[5];
        *(float4*)&Cv[8] = bp[6]; *(float4*)&Cv[12] = bp[7];
        float y = 0.f;
#pragma unroll
        for (int n = 0; n < DSTATE; ++n) {
          const float hn = __expf(dl * An[n]) * h[n] + dx * Bv[n];
          h[n] = hn;
          y += Cv[n] * hn;
        }
        y += dp * xv;
        const long zix = (long)row * (2 * DINNER) + DINNER + d;
        const float zz = xz0[zix] + part[zix];
        const float o = y * (zz / (1.f + __expf(-zz)));
        ybf[(long)row * DINNER + d] = f2bf(o);
      }
    }
    gridbar(bar, ++bcount);

    // ===== phase 4: out-proj split-K x4, relaxed atomicAdd into xf (residual inside) =====
    if (bid < 192) {
      const int ks = bid & 3, tile = bid >> 2;        // tile: 0..47
      gemm128<true>(ybf, woutbf + (size_t)l * DMODEL * DINNER, xf,
                    DMODEL, DINNER / 4, DINNER, DINNER, ks * (DINNER / 4),
                    tile & 7, tile >> 3, smem);
    }
    gridbar(bar, ++bcount);

    // ===== phase 5: cvt xf -> xbf (skip on last layer; rms reads xf) =====
    if (l < NLAYER - 1) {
      const int stride4 = MROWS * DMODEL / 4;
      for (int i = bid * 256 + tid; i < stride4; i += NBLK * 256) {
        float4 s = ((const float4*)xf)[i];
        ushort4 o; o.x = f2bf(s.x); o.y = f2bf(s.y); o.z = f2bf(s.z); o.w = f2bf(s.w);
        ((ushort4*)xbf)[i] = o;
      }
      gridbar(bar, ++bcount);
    }
  }

  // ===== final: RMSNorm(xf) -> bf16 (2 rows/block) =====
  {
    float* red = (float*)smem;
#pragma unroll 1
    for (int rr = 0; rr < 2; ++rr) {
      const int row = bid * 2 + rr;
      float v[3];
      float p = 0.f;
#pragma unroll
      for (int k = 0; k < 3; ++k) {
        const int i = row * DMODEL + tid + k * 256;
        float x = xf[i];
        v[k] = x;
        p += x * x;
      }
#pragma unroll
      for (int off2 = 32; off2; off2 >>= 1) p += __shfl_xor(p, off2, 64);
      const int wv = tid >> 6, lane = tid & 63;
      if (lane == 0) red[wv] = p;
      __syncthreads();
      if (tid == 0) {
        float tsum = red[0] + red[1] + red[2] + red[3];
        red[4] = rsqrtf(tsum / (float)DMODEL + 1e-5f);
      }
      __syncthreads();
      const float r = red[4];
#pragma unroll
      for (int k = 0; k < 3; ++k) {
        const int dd = tid + k * 256;
        xnbf[(long)row * DMODEL + dd] = f2bf(v[k] * r * normw[dd]);
      }
      __syncthreads();
    }
  }
}

// ---------------------------------------------------------------- 256^2 4-phase pipelined GEMM (logits, unchanged)
__global__ __launch_bounds__(512, 2) void gemm8_kern(
    const u16* __restrict__ A, const u16* __restrict__ B,
    float* __restrict__ C, int N, int K, int lda, int ldb)
{
  __shared__ u16 lds[2][2][256 * 64];
  const int tid = threadIdx.x;
  const int wave = tid >> 6;
  const int lane = tid & 63;
  const int wm = wave >> 2, wn = wave & 3;

  const int nwg = gridDim.x;
  const int q = nwg >> 3, r = nwg & 7;
  const int xcd = blockIdx.x & 7;
  const int t = (xcd < r ? xcd * (q + 1) : r * (q + 1) + (xcd - r) * q) + (blockIdx.x >> 3);
  const int m0 = (t & 3) * 256;
  const int n0 = (t >> 2) * 256;

  const int NT = K / 64;

  const int sblk = (((lane & 7) ^ (lane >> 3)) << 3);
  auto stage = [&](int buf, int ab, int half, int kt) {
    const u16* Mat = ab ? B : A;
    const int ld = ab ? ldb : lda;
    const int tb = ab ? n0 : m0;
#pragma unroll
    for (int j = 0; j < 2; ++j) {
      const int rloc = half * 128 + j * 64 + wave * 8;
      async16(Mat + (long)(tb + rloc + (lane >> 3)) * ld + kt * 64 + sblk,
              (char*)&lds[buf][ab][0] + (rloc << 7));
    }
  };

  bf16x8 af[4][2], bl[2][2], bh[2][2];
  const int aq = lane >> 4;
  auto readA = [&](int buf, int half) {
#pragma unroll
    for (int mf = 0; mf < 4; ++mf) {
      const int rr = half * 128 + wm * 64 + mf * 16 + (lane & 15);
#pragma unroll
      for (int ks = 0; ks < 2; ++ks) {
        const int q2 = ks * 4 + aq;
        af[mf][ks] = *(const bf16x8*)(&lds[buf][0][0] + rr * 64 + ((q2 ^ (rr & 7)) << 3));
      }
    }
  };
  auto readB = [&](int buf, int half, bf16x8 (&bf)[2][2]) {
#pragma unroll
    for (int nf = 0; nf < 2; ++nf) {
      const int rr = half * 128 + wn * 32 + nf * 16 + (lane & 15);
#pragma unroll
      for (int ks = 0; ks < 2; ++ks) {
        const int q2 = ks * 4 + aq;
        bf[nf][ks] = *(const bf16x8*)(&lds[buf][1][0] + rr * 64 + ((q2 ^ (rr & 7)) << 3));
      }
    }
  };

  f32x4 acc[8][4];
#pragma unroll
  for (int i = 0; i < 8; ++i)
#pragma unroll
    for (int j = 0; j < 4; ++j) acc[i][j] = (f32x4){0.f, 0.f, 0.f, 0.f};

#define MFMA16(QM, QN, BF)                                                        \
  __builtin_amdgcn_s_setprio(1);                                                  \
  _Pragma("unroll")                                                               \
  for (int mf = 0; mf < 4; ++mf)                                                  \
    _Pragma("unroll")                                                             \
    for (int nf = 0; nf < 2; ++nf)                                                \
      _Pragma("unroll")                                                           \
      for (int ks = 0; ks < 2; ++ks)                                              \
        acc[(QM)*4+mf][(QN)*2+nf] = __builtin_amdgcn_mfma_f32_16x16x32_bf16(      \
            af[mf][ks], BF[nf][ks], acc[(QM)*4+mf][(QN)*2+nf], 0, 0, 0);          \
  __builtin_amdgcn_s_setprio(0);

#define BAR()   asm volatile("" ::: "memory"); __builtin_amdgcn_s_barrier(); asm volatile("" ::: "memory")
#define WAITV(N) asm volatile("s_waitcnt vmcnt(" #N ")" ::: "memory"); __builtin_amdgcn_sched_barrier(0)
#define WAITL(N) asm volatile("s_waitcnt lgkmcnt(" #N ")" ::: "memory"); __builtin_amdgcn_sched_barrier(0)

  stage(0, 0, 0, 0); stage(0, 1, 0, 0); stage(0, 1, 1, 0); stage(0, 0, 1, 0);
  stage(1, 0, 0, 1); stage(1, 1, 0, 1); stage(1, 1, 1, 1);
  WAITV(6);
  BAR();
  readB(0, 0, bl);

#define TILE(KTE, BUF)                                                            \
  {                                                                               \
    const int kt = (KTE);                                                         \
    if (kt >= NT - 2) { WAITV(0); } else { WAITV(8); }                            \
    BAR();                                                                        \
    readA(BUF, 0);                                                                \
    readB(BUF, 1, bh);                                                            \
    if (kt + 1 < NT) stage(BUF ^ 1, 0, 1, kt + 1);                                \
    WAITL(4);                                                                     \
    MFMA16(0, 0, bl);                                                             \
    BAR();                                                                        \
    if (kt + 2 < NT) stage(BUF, 0, 0, kt + 2);                                    \
    WAITL(0);                                                                     \
    MFMA16(0, 1, bh);                                                             \
    if (kt >= NT - 2) { WAITV(0); } else { WAITV(10); }                           \
    BAR();                                                                        \
    readA(BUF, 1);                                                                \
    if (kt + 2 < NT) stage(BUF, 1, 0, kt + 2);                                    \
    WAITL(0);                                                                     \
    MFMA16(1, 0, bl);                                                             \
    if (kt >= NT - 2) { WAITV(0); } else { WAITV(8); }                            \
    BAR();                                                                        \
    if (kt + 1 < NT) readB(BUF ^ 1, 0, bl);                                       \
    if (kt + 2 < NT) stage(BUF, 1, 1, kt + 2);                                    \
    WAITL(4);                                                                     \
    MFMA16(1, 1, bh);                                                             \
  }

  for (int kt2 = 0; kt2 < NT; kt2 += 2) {
    TILE(kt2, 0);
    TILE(kt2 + 1, 1);
  }

#pragma unroll
  for (int qm = 0; qm < 2; ++qm)
#pragma unroll
    for (int mf = 0; mf < 4; ++mf)
#pragma unroll
      for (int qn = 0; qn < 2; ++qn)
#pragma unroll
        for (int nf = 0; nf < 2; ++nf) {
          const int col = n0 + qn * 128 + wn * 32 + nf * 16 + (lane & 15);
          if (col >= N) continue;
          const int row0 = m0 + qm * 128 + wm * 64 + mf * 16 + ((lane >> 4) << 2);
          const f32x4 v = acc[qm * 4 + mf][qn * 2 + nf];
#pragma unroll
          for (int rr2 = 0; rr2 < 4; ++rr2)
            C[(long)(row0 + rr2) * N + col] = v[rr2];
        }
#undef TILE
#undef MFMA16
#undef BAR
#undef WAITV
#undef WAITL
}

// ---------------------------------------------------------------- host
extern "C" void kernel_launch(void* const* d_in, const int* in_sizes, int n_in,
                              void* d_out, int out_size, void* d_ws, size_t ws_size,
                              hipStream_t stream)
{
  (void)in_sizes; (void)n_in; (void)out_size; (void)ws_size;
  const int*   idx   = (const int*)  d_in[0];
  const float* emb   = (const float*)d_in[1];
  const float* W_in  = (const float*)d_in[2];
  const float* convw = (const float*)d_in[3];
  const float* W_xp  = (const float*)d_in[4];
  const float* W_dt  = (const float*)d_in[5];
  const float* b_dt  = (const float*)d_in[6];
  const float* a_log = (const float*)d_in[7];
  const float* d_par = (const float*)d_in[8];
  const float* W_out = (const float*)d_in[9];
  const float* normw = (const float*)d_in[10];
  float* out = (float*)d_out;

  char* ws = (char*)d_ws;
  size_t off = 0;
  auto alloc = [&](size_t bytes) -> void* {
    void* p = ws + off;
    off += (bytes + 255) & ~(size_t)255;
    return p;
  };
  int*   bar    = (int*)  alloc(4096);
  u16*   embbf  = (u16*)  alloc((size_t)VPAD * DMODEL * 2);
  u16*   winbf  = (u16*)  alloc((size_t)NLAYER * 2 * DINNER * DMODEL * 2);
  u16*   woutbf = (u16*)  alloc((size_t)NLAYER * DMODEL * DINNER * 2);
  float* xf     = (float*)alloc((size_t)MROWS * DMODEL * 4);
  u16*   xbf    = (u16*)  alloc((size_t)MROWS * DMODEL * 2);
  float* xz0    = (float*)alloc((size_t)MROWS * 2 * DINNER * 4);
  float* xs     = (float*)alloc((size_t)MROWS * DINNER * 4);
  float* dlt    = (float*)alloc((size_t)MROWS * DINNER * 4);
  float* bc     = (float*)alloc((size_t)MROWS * 2 * DSTATE * 4);
  u16*   ybf    = (u16*)  alloc((size_t)MROWS * DINNER * 2);
  u16*   xnbf   = (u16*)  alloc((size_t)MROWS * DMODEL * 2);
  float* part   = (float*)alloc((size_t)MROWS * 2 * DINNER * 4);

  hipMemsetAsync(bar, 0, 4096, stream);
  mega_kern<<<NBLK, 256, 0, stream>>>(
      emb, W_in, W_out, idx, convw, W_xp, W_dt, b_dt, a_log, d_par, normw,
      embbf, winbf, woutbf, xbf, xf, xz0, xs, dlt, bc, ybf, xnbf, part, bar);
  gemm8_kern<<<4 * (VPAD / 256), 512, 0, stream>>>(
      xnbf, embbf, out, VV, DMODEL, DMODEL, DMODEL);
}

// Round 10
// 905.939 us; speedup vs baseline: 3.9025x; 1.8998x over previous
//
#include <hip/hip_runtime.h>
#include <cstdint>

#define VV     50257
#define VPAD   50432   // 197 * 256
#define DMODEL 768
#define NLAYER 4
#define DINNER 1536
#define DSTATE 16
#define DCONV  4
#define BATCH  2
#define SEQ    512
#define MROWS  (BATCH*SEQ)   // 1024

typedef unsigned short u16;
typedef __attribute__((ext_vector_type(8))) short bf16x8;
typedef __attribute__((ext_vector_type(4))) float f32x4;

__device__ __forceinline__ u16 f2bf(float f) {
  unsigned u = __float_as_uint(f);
  u += 0x7fffu + ((u >> 16) & 1u);
  return (u16)(u >> 16);
}

__device__ __forceinline__ void async16(const void* g, void* l) {
  auto gp = reinterpret_cast<const __attribute__((address_space(1))) unsigned int*>(
      reinterpret_cast<uintptr_t>(g));
  auto lp = reinterpret_cast<__attribute__((address_space(3))) unsigned int*>(
      reinterpret_cast<uintptr_t>(l));
  __builtin_amdgcn_global_load_lds(gp, lp, 16, 0, 0);
}

// ---------------------------------------------------------------- fused prep
__global__ void prep_kern(const float* __restrict__ emb, const float* __restrict__ W_in,
                          const float* __restrict__ W_out, const int* __restrict__ idx,
                          u16* __restrict__ embbf, u16* __restrict__ winbf,
                          u16* __restrict__ woutbf, float* __restrict__ xf,
                          u16* __restrict__ xbf) {
  const int E4  = VPAD * DMODEL / 4;
  const int W14 = NLAYER * 2 * DINNER * DMODEL / 4;
  const int W24 = NLAYER * DMODEL * DINNER / 4;
  const int X4  = MROWS * DMODEL / 4;
  const int TOT = E4 + W14 + W24 + X4;
  int i = blockIdx.x * blockDim.x + threadIdx.x;
  const int stride = gridDim.x * blockDim.x;
  for (; i < TOT; i += stride) {
    if (i < E4) {
      ushort4 o;
      if (i < VV * DMODEL / 4) {
        float4 v = *(const float4*)(emb + (long)i * 4);
        o.x = f2bf(v.x); o.y = f2bf(v.y); o.z = f2bf(v.z); o.w = f2bf(v.w);
      } else { o.x = 0; o.y = 0; o.z = 0; o.w = 0; }
      *(ushort4*)(embbf + (long)i * 4) = o;
    } else if (i < E4 + W14) {
      const int j = i - E4;
      float4 v = *(const float4*)(W_in + (long)j * 4);
      ushort4 o; o.x = f2bf(v.x); o.y = f2bf(v.y); o.z = f2bf(v.z); o.w = f2bf(v.w);
      *(ushort4*)(winbf + (long)j * 4) = o;
    } else if (i < E4 + W14 + W24) {
      const int j = i - E4 - W14;
      float4 v = *(const float4*)(W_out + (long)j * 4);
      ushort4 o; o.x = f2bf(v.x); o.y = f2bf(v.y); o.z = f2bf(v.z); o.w = f2bf(v.w);
      *(ushort4*)(woutbf + (long)j * 4) = o;
    } else {
      const int j = i - E4 - W14 - W24;
      const int r = j / (DMODEL / 4);
      const int c = (j % (DMODEL / 4)) * 4;
      const int id = idx[r];
      float4 v = *(const float4*)(emb + (long)id * DMODEL + c);
      *(float4*)(xf + (long)r * DMODEL + c) = v;
      ushort4 o; o.x = f2bf(v.x); o.y = f2bf(v.y); o.z = f2bf(v.z); o.w = f2bf(v.w);
      *(ushort4*)(xbf + (long)r * DMODEL + c) = o;
    }
  }
}

// ---------------------------------------------------------------- 128^2 ring-3 GEMM (per-layer)
template<bool GUARDN, bool XSWZ>
__global__ __launch_bounds__(256) void gemm3_kern(
    const u16* __restrict__ A, const u16* __restrict__ B,
    float* __restrict__ C, int M, int N, int K, int lda, int ldb)
{
  __shared__ u16 As[3][128 * 32];
  __shared__ u16 Bs[3][128 * 32];
  int bx, by;
  if (XSWZ) {
    const int nt = gridDim.x >> 3;
    const int t = (blockIdx.x & 7) * nt + (blockIdx.x >> 3);
    bx = t & 7; by = t >> 3;
  } else { bx = blockIdx.x; by = blockIdx.y; }
  const int koff = blockIdx.z * K;
  const long coff = (long)blockIdx.z * M * N;

  const int tid  = threadIdx.x;
  const int wave = tid >> 6;
  const int lane = tid & 63;
  const int wr = wave >> 1, wc = wave & 1;
  const int m0 = bx * 128;
  const int n0 = by * 128;

  const int srow = wave * 32 + (lane >> 2);
  const int sblk = ((lane & 3) ^ ((lane >> 3) & 3)) * 8;

  f32x4 acc[4][4];
#pragma unroll
  for (int i = 0; i < 4; ++i)
#pragma unroll
    for (int j = 0; j < 4; ++j) acc[i][j] = (f32x4){0.f, 0.f, 0.f, 0.f};

  const int arow = wr * 64 + (lane & 15);
  const int brow = wc * 64 + (lane & 15);
  const int sa   = (((lane >> 4) ^ ((lane >> 1) & 3)) << 3);

  const int KT = K / 32;
  auto stage = [&](int kt) {
    const int slot = kt % 3;
    const long kcol = (long)koff + kt * 32;
#pragma unroll
    for (int j = 0; j < 2; ++j) {
      async16(A + (long)(m0 + srow + j * 16) * lda + kcol + sblk,
              (char*)(As[slot]) + (wave * 32 + j * 16) * 64);
      async16(B + (long)(n0 + srow + j * 16) * ldb + kcol + sblk,
              (char*)(Bs[slot]) + (wave * 32 + j * 16) * 64);
    }
  };

  stage(0);
  stage(1);
  for (int t = 0; t < KT; ++t) {
    if (t + 2 < KT) {
      stage(t + 2);
      asm volatile("s_waitcnt vmcnt(8)" ::: "memory");
    } else if (t + 2 == KT) {
      asm volatile("s_waitcnt vmcnt(4)" ::: "memory");
    } else {
      asm volatile("s_waitcnt vmcnt(0)" ::: "memory");
    }
    __builtin_amdgcn_s_barrier();
    asm volatile("" ::: "memory");

    const u16* as = As[t % 3];
    const u16* bs = Bs[t % 3];
    bf16x8 af[4], bv[4];
#pragma unroll
    for (int i = 0; i < 4; ++i) af[i] = *(const bf16x8*)(as + (arow + 16 * i) * 32 + sa);
#pragma unroll
    for (int j = 0; j < 4; ++j) bv[j] = *(const bf16x8*)(bs + (brow + 16 * j) * 32 + sa);

    __builtin_amdgcn_s_setprio(1);
#pragma unroll
    for (int i = 0; i < 4; ++i)
#pragma unroll
      for (int j = 0; j < 4; ++j)
        acc[i][j] = __builtin_amdgcn_mfma_f32_16x16x32_bf16(af[i], bv[j], acc[i][j], 0, 0, 0);
    __builtin_amdgcn_s_setprio(0);

    asm volatile("" ::: "memory");
    __builtin_amdgcn_s_barrier();
    asm volatile("" ::: "memory");
  }

  const int rbase = m0 + wr * 64 + ((lane >> 4) << 2);
  const int cbase = n0 + wc * 64 + (lane & 15);
#pragma unroll
  for (int j = 0; j < 4; ++j) {
    const int col = cbase + j * 16;
    if (GUARDN && col >= N) continue;
#pragma unroll
    for (int i = 0; i < 4; ++i) {
#pragma unroll
      for (int r = 0; r < 4; ++r) {
        const int row = rbase + i * 16 + r;
        C[coff + (long)row * N + col] = acc[i][j][r];
      }
    }
  }
}

// ---------------------------------------------------------------- persistent 256^2 1-barrier/K-tile GEMM (logits)
// 8 waves (2M x 4N). Per K-tile: stage(kt+1 -> buf^1); vmcnt(8); read frags; lgkm(0);
// 64 MFMA (qm-split for VGPR); ONE s_barrier. Persistent: block owns 3-4 tiles on its
// XCD's contiguous N-panels; next tile's first stage issued before epilogue stores.
__global__ __launch_bounds__(512, 2) void gemm8p_kern(
    const u16* __restrict__ A, const u16* __restrict__ B,
    float* __restrict__ C, int N, int K, int lda, int ldb)
{
  __shared__ u16 lds[2][2][256 * 64];   // [buf][A/B][256 rows x 64 cols]
  const int tid = threadIdx.x;
  const int wave = tid >> 6;
  const int lane = tid & 63;
  const int wm = wave >> 2, wn = wave & 3;
  const int NT = K / 64;                // 12

  const int xcd = blockIdx.x & 7;
  const int lin = blockIdx.x >> 3;      // 0..31
  const int NTILES = 4 * (VPAD / 256);  // 788; tile u: n-panel u>>2, m-tile u&3
  const int qq = NTILES / 8, rr8 = NTILES % 8;
  const int cnt = qq + (xcd < rr8 ? 1 : 0);
  const int base = xcd * qq + (xcd < rr8 ? xcd : rr8);

  const int sblk = (((lane & 7) ^ (lane >> 3)) << 3);
  auto stage = [&](int buf, int kt, int m0, int n0) {
#pragma unroll
    for (int half = 0; half < 2; ++half)
#pragma unroll
      for (int j = 0; j < 2; ++j) {
        const int rloc = half * 128 + j * 64 + wave * 8;     // wave-uniform
        async16(A + (long)(m0 + rloc + (lane >> 3)) * lda + kt * 64 + sblk,
                (char*)&lds[buf][0][0] + (rloc << 7));
        async16(B + (long)(n0 + rloc + (lane >> 3)) * ldb + kt * 64 + sblk,
                (char*)&lds[buf][1][0] + (rloc << 7));
      }
  };

  const int aq = lane >> 4;
  bf16x8 af[4][2], bb[4][2];
  auto readA = [&](int buf, int qm) {
#pragma unroll
    for (int mf = 0; mf < 4; ++mf) {
      const int rr = qm * 128 + wm * 64 + mf * 16 + (lane & 15);
#pragma unroll
      for (int ks = 0; ks < 2; ++ks) {
        const int q2 = ks * 4 + aq;
        af[mf][ks] = *(const bf16x8*)(&lds[buf][0][0] + rr * 64 + ((q2 ^ (rr & 7)) << 3));
      }
    }
  };
  auto readB = [&](int buf) {
#pragma unroll
    for (int qn = 0; qn < 2; ++qn)
#pragma unroll
      for (int nf = 0; nf < 2; ++nf) {
        const int rr = qn * 128 + wn * 32 + nf * 16 + (lane & 15);
#pragma unroll
        for (int ks = 0; ks < 2; ++ks) {
          const int q2 = ks * 4 + aq;
          bb[qn * 2 + nf][ks] = *(const bf16x8*)(&lds[buf][1][0] + rr * 64 + ((q2 ^ (rr & 7)) << 3));
        }
      }
  };

#define WAITV(NN) asm volatile("s_waitcnt vmcnt(" #NN ")" ::: "memory"); __builtin_amdgcn_sched_barrier(0)
#define WAITL0()  asm volatile("s_waitcnt lgkmcnt(0)" ::: "memory"); __builtin_amdgcn_sched_barrier(0)

  bool first = true;
  for (int u = base + lin; u < base + cnt; u += 32) {
    const int m0 = (u & 3) * 256;
    const int n0 = (u >> 2) * 256;

    f32x4 acc[8][4];
#pragma unroll
    for (int i = 0; i < 8; ++i)
#pragma unroll
      for (int j = 0; j < 4; ++j) acc[i][j] = (f32x4){0.f, 0.f, 0.f, 0.f};

    if (first) { stage(0, 0, m0, n0); first = false; }   // else issued before prev epilogue

    for (int kt = 0; kt < NT; ++kt) {
      const int buf = kt & 1;
      if (kt + 1 < NT) {
        stage(buf ^ 1, kt + 1, m0, n0);
        WAITV(8);                       // force kt's 8 loads done; kt+1's 8 stay in flight
      } else {
        WAITV(0);
      }
      __builtin_amdgcn_s_barrier();     // kt data visible to all waves; buf^1 free to fill
      asm volatile("" ::: "memory");

      readB(buf);
      readA(buf, 0);
      WAITL0();
      __builtin_amdgcn_s_setprio(1);
#pragma unroll
      for (int mf = 0; mf < 4; ++mf)
#pragma unroll
        for (int qn = 0; qn < 2; ++qn)
#pragma unroll
          for (int nf = 0; nf < 2; ++nf)
#pragma unroll
            for (int ks = 0; ks < 2; ++ks)
              acc[mf][qn * 2 + nf] = __builtin_amdgcn_mfma_f32_16x16x32_bf16(
                  af[mf][ks], bb[qn * 2 + nf][ks], acc[mf][qn * 2 + nf], 0, 0, 0);
      __builtin_amdgcn_s_setprio(0);

      readA(buf, 1);
      WAITL0();
      __builtin_amdgcn_s_setprio(1);
#pragma unroll
      for (int mf = 0; mf < 4; ++mf)
#pragma unroll
        for (int qn = 0; qn < 2; ++qn)
#pragma unroll
          for (int nf = 0; nf < 2; ++nf)
#pragma unroll
            for (int ks = 0; ks < 2; ++ks)
              acc[4 + mf][qn * 2 + nf] = __builtin_amdgcn_mfma_f32_16x16x32_bf16(
                  af[mf][ks], bb[qn * 2 + nf][ks], acc[4 + mf][qn * 2 + nf], 0, 0, 0);
      __builtin_amdgcn_s_setprio(0);

      asm volatile("" ::: "memory");
      __builtin_amdgcn_s_barrier();     // all reads of buf done before next iter writes it
      asm volatile("" ::: "memory");
    }

    // overlap: issue next tile's first stage before this tile's stores
    const int un = u + 32;
    if (un < base + cnt) {
      stage(0, 0, (un & 3) * 256, (un >> 2) * 256);
    }

    // epilogue: C-write (fp32), col-guard against VV
#pragma unroll
    for (int qm = 0; qm < 2; ++qm)
#pragma unroll
      for (int mf = 0; mf < 4; ++mf)
#pragma unroll
        for (int qn = 0; qn < 2; ++qn)
#pragma unroll
          for (int nf = 0; nf < 2; ++nf) {
            const int col = n0 + qn * 128 + wn * 32 + nf * 16 + (lane & 15);
            if (col >= N) continue;
            const int row0 = m0 + qm * 128 + wm * 64 + mf * 16 + ((lane >> 4) << 2);
            const f32x4 v = acc[qm * 4 + mf][qn * 2 + nf];
#pragma unroll
            for (int rr2 = 0; rr2 < 4; ++rr2)
              C[(long)(row0 + rr2) * N + col] = v[rr2];
          }
  }
#undef WAITV
#undef WAITL0
}

// ---------------------------------------------------------------- split-K reduce + residual + bf16
__global__ __launch_bounds__(256) void redout_kern(const float* __restrict__ part,
                                                   float* __restrict__ xf,
                                                   u16* __restrict__ xbf) {
  const int i = blockIdx.x * blockDim.x + threadIdx.x;
  if (i >= MROWS * DMODEL / 4) return;
  const int stride4 = MROWS * DMODEL / 4;
  float4 s = ((const float4*)part)[i];
  float4 p1 = ((const float4*)part)[i + stride4];
  float4 p2 = ((const float4*)part)[i + 2 * stride4];
  float4 p3 = ((const float4*)part)[i + 3 * stride4];
  float4 x = ((const float4*)xf)[i];
  s.x += p1.x + p2.x + p3.x + x.x;
  s.y += p1.y + p2.y + p3.y + x.y;
  s.z += p1.z + p2.z + p3.z + x.z;
  s.w += p1.w + p2.w + p3.w + x.w;
  ((float4*)xf)[i] = s;
  ushort4 o; o.x = f2bf(s.x); o.y = f2bf(s.y); o.z = f2bf(s.z); o.w = f2bf(s.w);
  ((ushort4*)xbf)[i] = o;
}

// ---------------------------------------------------------------- fused conv+SiLU+xproj+delta
__global__ __launch_bounds__(256) void convxproj_kern(
    const float* __restrict__ xz, const float* __restrict__ cw,
    const float* __restrict__ Wx, const float* __restrict__ wdt,
    const float* __restrict__ bdt,
    float* __restrict__ xs, float* __restrict__ dlt, float* __restrict__ bc)
{
  __shared__ float sx[DINNER];
  __shared__ float sxp[40];
  const int row = blockIdx.x;
  const int t = row & (SEQ - 1);
  const int tid = threadIdx.x;

  for (int c = tid; c < DINNER; c += 256) {
    const float* w = cw + c * DCONV;
    float a = 0.f;
#pragma unroll
    for (int k = 0; k < DCONV; ++k) {
      const int tt = t - (DCONV - 1) + k;
      if (tt >= 0) a += w[k] * xz[(long)(row - (DCONV - 1) + k) * (2 * DINNER) + c];
    }
    const float s = a / (1.f + __expf(-a));
    sx[c] = s;
    xs[(long)row * DINNER + c] = s;
  }
  __syncthreads();

  const int wv = tid >> 6, lane = tid & 63;
  for (int e = wv; e < 2 * DSTATE + 1; e += 4) {
    const float* We = Wx + (long)e * DINNER;
    float p = 0.f;
    for (int d = lane; d < DINNER; d += 64) p += sx[d] * We[d];
#pragma unroll
    for (int off = 32; off; off >>= 1) p += __shfl_xor(p, off, 64);
    if (lane == 0) sxp[e] = p;
  }
  __syncthreads();
  const float dtr = sxp[0];
  for (int d = tid; d < DINNER; d += 256) {
    float v = dtr * wdt[d] + bdt[d];
    float sp = (v > 15.f) ? v : log1pf(__expf(v));
    dlt[(long)row * DINNER + d] = sp;
  }
  if (tid < 2 * DSTATE) bc[(long)row * (2 * DSTATE) + tid] = sxp[1 + tid];
}

// ---------------------------------------------------------------- chunked selective scan + gate
__global__ __launch_bounds__(128) void scan_kern(
    const float* __restrict__ dlt, const float* __restrict__ bc,
    const float* __restrict__ xs, const float* __restrict__ xz,
    const float* __restrict__ alog, const float* __restrict__ dpar,
    u16* __restrict__ ybf)
{
  __shared__ float sh_h[16][8][DSTATE];
  __shared__ float sh_s[16][8];
  const int tid = threadIdx.x;
  const int ch = tid & 7, chunk = tid >> 3;
  const int ch_abs = blockIdx.x * 8 + ch;
  const int b = ch_abs / DINNER, d = ch_abs % DINNER;
  float An[DSTATE];
#pragma unroll
  for (int n = 0; n < DSTATE; ++n) An[n] = -__expf(alog[(long)d * DSTATE + n]);
  const int r0 = b * SEQ + chunk * 32;

  float h[DSTATE];
#pragma unroll
  for (int n = 0; n < DSTATE; ++n) h[n] = 0.f;
  float ssum = 0.f;
  for (int s = 0; s < 32; ++s) {
    const int row = r0 + s;
    const float dl = dlt[(long)row * DINNER + d];
    const float xv = xs[(long)row * DINNER + d];
    const float dx = dl * xv;
    const float4* bp = (const float4*)(bc + (long)row * (2 * DSTATE));
    float Bv[DSTATE];
    *(float4*)&Bv[0]  = bp[0]; *(float4*)&Bv[4]  = bp[1];
    *(float4*)&Bv[8]  = bp[2]; *(float4*)&Bv[12] = bp[3];
    ssum += dl;
#pragma unroll
    for (int n = 0; n < DSTATE; ++n) h[n] = __expf(dl * An[n]) * h[n] + dx * Bv[n];
  }
#pragma unroll
  for (int n = 0; n < DSTATE; ++n) sh_h[chunk][ch][n] = h[n];
  sh_s[chunk][ch] = ssum;
  __syncthreads();

  {
    const int n2 = tid & 15, ch2 = tid >> 4;
    const int d2 = (blockIdx.x * 8 + ch2) % DINNER;
    const float A2 = -__expf(alog[(long)d2 * DSTATE + n2]);
    float carry = 0.f;
    for (int c = 0; c < 16; ++c) {
      const float hl = sh_h[c][ch2][n2];
      sh_h[c][ch2][n2] = carry;
      carry = __expf(A2 * sh_s[c][ch2]) * carry + hl;
    }
  }
  __syncthreads();

#pragma unroll
  for (int n = 0; n < DSTATE; ++n) h[n] = sh_h[chunk][ch][n];
  const float dp = dpar[d];
  for (int s = 0; s < 32; ++s) {
    const int row = r0 + s;
    const float dl = dlt[(long)row * DINNER + d];
    const float xv = xs[(long)row * DINNER + d];
    const float dx = dl * xv;
    const float4* bp = (const float4*)(bc + (long)row * (2 * DSTATE));
    float Bv[DSTATE], Cv[DSTATE];
    *(float4*)&Bv[0]  = bp[0]; *(float4*)&Bv[4]  = bp[1];
    *(float4*)&Bv[8]  = bp[2]; *(float4*)&Bv[12] = bp[3];
    *(float4*)&Cv[0]  = bp[4]; *(float4*)&Cv[4]  = bp[5];
    *(float4*)&Cv[8]  = bp[6]; *(float4*)&Cv[12] = bp[7];
    float y = 0.f;
#pragma unroll
    for (int n = 0; n < DSTATE; ++n) {
      const float hn = __expf(dl * An[n]) * h[n] + dx * Bv[n];
      h[n] = hn;
      y += Cv[n] * hn;
    }
    y += dp * xv;
    const float zz = xz[(long)row * (2 * DINNER) + DINNER + d];
    const float o = y * (zz / (1.f + __expf(-zz)));
    ybf[(long)row * DINNER + d] = f2bf(o);
  }
}

// ---------------------------------------------------------------- fused last-redout + RMSNorm -> bf16
__global__ __launch_bounds__(256) void rmsfuse_kern(const float* __restrict__ part,
                                                    const float* __restrict__ xf,
                                                    const float* __restrict__ nw,
                                                    u16* __restrict__ xnbf) {
  const int row = blockIdx.x, tid = threadIdx.x;
  const int S = MROWS * DMODEL;
  float v[3];
  float p = 0.f;
#pragma unroll
  for (int k = 0; k < 3; ++k) {
    const int i = row * DMODEL + tid + k * 256;
    float x = xf[i] + part[i] + part[i + S] + part[i + 2 * S] + part[i + 3 * S];
    v[k] = x;
    p += x * x;
  }
#pragma unroll
  for (int off = 32; off; off >>= 1) p += __shfl_xor(p, off, 64);
  __shared__ float red[4];
  __shared__ float s_rms;
  const int wv = tid >> 6, lane = tid & 63;
  if (lane == 0) red[wv] = p;
  __syncthreads();
  if (tid == 0) {
    float tsum = red[0] + red[1] + red[2] + red[3];
    s_rms = rsqrtf(tsum / (float)DMODEL + 1e-5f);
  }
  __syncthreads();
  const float r = s_rms;
#pragma unroll
  for (int k = 0; k < 3; ++k) {
    const int dd = tid + k * 256;
    xnbf[(long)row * DMODEL + dd] = f2bf(v[k] * r * nw[dd]);
  }
}

// ---------------------------------------------------------------- host
extern "C" void kernel_launch(void* const* d_in, const int* in_sizes, int n_in,
                              void* d_out, int out_size, void* d_ws, size_t ws_size,
                              hipStream_t stream)
{
  (void)in_sizes; (void)n_in; (void)out_size; (void)ws_size;
  const int*   idx   = (const int*)  d_in[0];
  const float* emb   = (const float*)d_in[1];
  const float* W_in  = (const float*)d_in[2];
  const float* convw = (const float*)d_in[3];
  const float* W_xp  = (const float*)d_in[4];
  const float* W_dt  = (const float*)d_in[5];
  const float* b_dt  = (const float*)d_in[6];
  const float* a_log = (const float*)d_in[7];
  const float* d_par = (const float*)d_in[8];
  const float* W_out = (const float*)d_in[9];
  const float* normw = (const float*)d_in[10];
  float* out = (float*)d_out;

  char* ws = (char*)d_ws;
  size_t off = 0;
  auto alloc = [&](size_t bytes) -> void* {
    void* p = ws + off;
    off += (bytes + 255) & ~(size_t)255;
    return p;
  };
  u16*   embbf  = (u16*)  alloc((size_t)VPAD * DMODEL * 2);
  u16*   winbf  = (u16*)  alloc((size_t)NLAYER * 2 * DINNER * DMODEL * 2);
  u16*   woutbf = (u16*)  alloc((size_t)NLAYER * DMODEL * DINNER * 2);
  float* xf     = (float*)alloc((size_t)MROWS * DMODEL * 4);
  u16*   xbf    = (u16*)  alloc((size_t)MROWS * DMODEL * 2);
  float* xz     = (float*)alloc((size_t)MROWS * 2 * DINNER * 4);
  float* xs     = (float*)alloc((size_t)MROWS * DINNER * 4);
  float* dlt    = (float*)alloc((size_t)MROWS * DINNER * 4);
  float* bc     = (float*)alloc((size_t)MROWS * 2 * DSTATE * 4);
  u16*   ybf    = (u16*)  alloc((size_t)MROWS * DINNER * 2);
  u16*   xnbf   = (u16*)  alloc((size_t)MROWS * DMODEL * 2);
  float* part   = (float*)alloc((size_t)4 * MROWS * DMODEL * 4);

  prep_kern<<<2048, 256, 0, stream>>>(emb, W_in, W_out, idx, embbf, winbf, woutbf, xf, xbf);

  for (int l = 0; l < NLAYER; ++l) {
    gemm3_kern<false, true><<<8 * (2 * DINNER / 128), 256, 0, stream>>>(
        xbf, winbf + (size_t)l * 2 * DINNER * DMODEL, xz,
        MROWS, 2 * DINNER, DMODEL, DMODEL, DMODEL);
    convxproj_kern<<<MROWS, 256, 0, stream>>>(
        xz, convw + (size_t)l * DINNER * DCONV,
        W_xp + (size_t)l * (2 * DSTATE + 1) * DINNER,
        W_dt + (size_t)l * DINNER, b_dt + (size_t)l * DINNER, xs, dlt, bc);
    scan_kern<<<BATCH * DINNER / 8, 128, 0, stream>>>(
        dlt, bc, xs, xz, a_log + (size_t)l * DINNER * DSTATE, d_par + (size_t)l * DINNER, ybf);
    gemm3_kern<false, true><<<dim3(8 * (DMODEL / 128), 1, 4), 256, 0, stream>>>(
        ybf, woutbf + (size_t)l * DMODEL * DINNER, part,
        MROWS, DMODEL, DINNER / 4, DINNER, DINNER);
    if (l < NLAYER - 1)
      redout_kern<<<MROWS * DMODEL / 4 / 256, 256, 0, stream>>>(part, xf, xbf);
  }
  rmsfuse_kern<<<MROWS, 256, 0, stream>>>(part, xf, normw, xnbf);
  // logits = xn @ emb^T  (M=1024, N=50257, K=768), persistent 1-barrier/K-tile
  gemm8p_kern<<<256, 512, 0, stream>>>(
      xnbf, embbf, out, VV, DMODEL, DMODEL, DMODEL);
}

// Round 11
// 794.477 us; speedup vs baseline: 4.4500x; 1.1403x over previous
//
#include <hip/hip_runtime.h>
#include <cstdint>

#define VV     50257
#define VPAD   50432   // 197 * 256
#define DMODEL 768
#define NLAYER 4
#define DINNER 1536
#define DSTATE 16
#define DCONV  4
#define BATCH  2
#define SEQ    512
#define MROWS  (BATCH*SEQ)   // 1024
#define XZS    ((long)MROWS * 2 * DINNER)   // xz partial-slice stride (elements)

typedef unsigned short u16;
typedef __attribute__((ext_vector_type(8))) short bf16x8;
typedef __attribute__((ext_vector_type(4))) float f32x4;

__device__ __forceinline__ u16 f2bf(float f) {
  unsigned u = __float_as_uint(f);
  u += 0x7fffu + ((u >> 16) & 1u);
  return (u16)(u >> 16);
}

__device__ __forceinline__ void async16(const void* g, void* l) {
  auto gp = reinterpret_cast<const __attribute__((address_space(1))) unsigned int*>(
      reinterpret_cast<uintptr_t>(g));
  auto lp = reinterpret_cast<__attribute__((address_space(3))) unsigned int*>(
      reinterpret_cast<uintptr_t>(l));
  __builtin_amdgcn_global_load_lds(gp, lp, 16, 0, 0);
}

// ---------------------------------------------------------------- fused prep
__global__ void prep_kern(const float* __restrict__ emb, const float* __restrict__ W_in,
                          const float* __restrict__ W_out, const int* __restrict__ idx,
                          u16* __restrict__ embbf, u16* __restrict__ winbf,
                          u16* __restrict__ woutbf, float* __restrict__ xf,
                          u16* __restrict__ xbf) {
  const int E4  = VPAD * DMODEL / 4;
  const int W14 = NLAYER * 2 * DINNER * DMODEL / 4;
  const int W24 = NLAYER * DMODEL * DINNER / 4;
  const int X4  = MROWS * DMODEL / 4;
  const int TOT = E4 + W14 + W24 + X4;
  int i = blockIdx.x * blockDim.x + threadIdx.x;
  const int stride = gridDim.x * blockDim.x;
  for (; i < TOT; i += stride) {
    if (i < E4) {
      ushort4 o;
      if (i < VV * DMODEL / 4) {
        float4 v = *(const float4*)(emb + (long)i * 4);
        o.x = f2bf(v.x); o.y = f2bf(v.y); o.z = f2bf(v.z); o.w = f2bf(v.w);
      } else { o.x = 0; o.y = 0; o.z = 0; o.w = 0; }
      *(ushort4*)(embbf + (long)i * 4) = o;
    } else if (i < E4 + W14) {
      const int j = i - E4;
      float4 v = *(const float4*)(W_in + (long)j * 4);
      ushort4 o; o.x = f2bf(v.x); o.y = f2bf(v.y); o.z = f2bf(v.z); o.w = f2bf(v.w);
      *(ushort4*)(winbf + (long)j * 4) = o;
    } else if (i < E4 + W14 + W24) {
      const int j = i - E4 - W14;
      float4 v = *(const float4*)(W_out + (long)j * 4);
      ushort4 o; o.x = f2bf(v.x); o.y = f2bf(v.y); o.z = f2bf(v.z); o.w = f2bf(v.w);
      *(ushort4*)(woutbf + (long)j * 4) = o;
    } else {
      const int j = i - E4 - W14 - W24;
      const int r = j / (DMODEL / 4);
      const int c = (j % (DMODEL / 4)) * 4;
      const int id = idx[r];
      float4 v = *(const float4*)(emb + (long)id * DMODEL + c);
      *(float4*)(xf + (long)r * DMODEL + c) = v;
      ushort4 o; o.x = f2bf(v.x); o.y = f2bf(v.y); o.z = f2bf(v.z); o.w = f2bf(v.w);
      *(ushort4*)(xbf + (long)r * DMODEL + c) = o;
    }
  }
}

// ---------------------------------------------------------------- 128^2 ring-3 GEMM (per-layer)
// blockIdx.z = split-K slice: A/B col offset z*K, C offset z*M*N.
template<bool GUARDN, bool XSWZ>
__global__ __launch_bounds__(256) void gemm3_kern(
    const u16* __restrict__ A, const u16* __restrict__ B,
    float* __restrict__ C, int M, int N, int K, int lda, int ldb)
{
  __shared__ u16 As[3][128 * 32];
  __shared__ u16 Bs[3][128 * 32];
  int bx, by;
  if (XSWZ) {
    const int nt = gridDim.x >> 3;
    const int t = (blockIdx.x & 7) * nt + (blockIdx.x >> 3);
    bx = t & 7; by = t >> 3;
  } else { bx = blockIdx.x; by = blockIdx.y; }
  const int koff = blockIdx.z * K;
  const long coff = (long)blockIdx.z * M * N;

  const int tid  = threadIdx.x;
  const int wave = tid >> 6;
  const int lane = tid & 63;
  const int wr = wave >> 1, wc = wave & 1;
  const int m0 = bx * 128;
  const int n0 = by * 128;

  const int srow = wave * 32 + (lane >> 2);
  const int sblk = ((lane & 3) ^ ((lane >> 3) & 3)) * 8;

  f32x4 acc[4][4];
#pragma unroll
  for (int i = 0; i < 4; ++i)
#pragma unroll
    for (int j = 0; j < 4; ++j) acc[i][j] = (f32x4){0.f, 0.f, 0.f, 0.f};

  const int arow = wr * 64 + (lane & 15);
  const int brow = wc * 64 + (lane & 15);
  const int sa   = (((lane >> 4) ^ ((lane >> 1) & 3)) << 3);

  const int KT = K / 32;
  auto stage = [&](int kt) {
    const int slot = kt % 3;
    const long kcol = (long)koff + kt * 32;
#pragma unroll
    for (int j = 0; j < 2; ++j) {
      async16(A + (long)(m0 + srow + j * 16) * lda + kcol + sblk,
              (char*)(As[slot]) + (wave * 32 + j * 16) * 64);
      async16(B + (long)(n0 + srow + j * 16) * ldb + kcol + sblk,
              (char*)(Bs[slot]) + (wave * 32 + j * 16) * 64);
    }
  };

  stage(0);
  stage(1);
  for (int t = 0; t < KT; ++t) {
    if (t + 2 < KT) {
      stage(t + 2);
      asm volatile("s_waitcnt vmcnt(8)" ::: "memory");
    } else if (t + 2 == KT) {
      asm volatile("s_waitcnt vmcnt(4)" ::: "memory");
    } else {
      asm volatile("s_waitcnt vmcnt(0)" ::: "memory");
    }
    __builtin_amdgcn_s_barrier();
    asm volatile("" ::: "memory");

    const u16* as = As[t % 3];
    const u16* bs = Bs[t % 3];
    bf16x8 af[4], bv[4];
#pragma unroll
    for (int i = 0; i < 4; ++i) af[i] = *(const bf16x8*)(as + (arow + 16 * i) * 32 + sa);
#pragma unroll
    for (int j = 0; j < 4; ++j) bv[j] = *(const bf16x8*)(bs + (brow + 16 * j) * 32 + sa);

    __builtin_amdgcn_s_setprio(1);
#pragma unroll
    for (int i = 0; i < 4; ++i)
#pragma unroll
      for (int j = 0; j < 4; ++j)
        acc[i][j] = __builtin_amdgcn_mfma_f32_16x16x32_bf16(af[i], bv[j], acc[i][j], 0, 0, 0);
    __builtin_amdgcn_s_setprio(0);

    asm volatile("" ::: "memory");
    __builtin_amdgcn_s_barrier();
    asm volatile("" ::: "memory");
  }

  const int rbase = m0 + wr * 64 + ((lane >> 4) << 2);
  const int cbase = n0 + wc * 64 + (lane & 15);
#pragma unroll
  for (int j = 0; j < 4; ++j) {
    const int col = cbase + j * 16;
    if (GUARDN && col >= N) continue;
#pragma unroll
    for (int i = 0; i < 4; ++i) {
#pragma unroll
      for (int r = 0; r < 4; ++r) {
        const int row = rbase + i * 16 + r;
        C[coff + (long)row * N + col] = acc[i][j][r];
      }
    }
  }
}

// ---------------------------------------------------------------- 256^2 4-phase pipelined GEMM (logits; R5-proven, 128us)
__global__ __launch_bounds__(512, 2) void gemm8_kern(
    const u16* __restrict__ A, const u16* __restrict__ B,
    float* __restrict__ C, int N, int K, int lda, int ldb)
{
  __shared__ u16 lds[2][2][256 * 64];
  const int tid = threadIdx.x;
  const int wave = tid >> 6;
  const int lane = tid & 63;
  const int wm = wave >> 2, wn = wave & 3;

  const int nwg = gridDim.x;
  const int q = nwg >> 3, r = nwg & 7;
  const int xcd = blockIdx.x & 7;
  const int t = (xcd < r ? xcd * (q + 1) : r * (q + 1) + (xcd - r) * q) + (blockIdx.x >> 3);
  const int m0 = (t & 3) * 256;
  const int n0 = (t >> 2) * 256;

  const int NT = K / 64;

  const int sblk = (((lane & 7) ^ (lane >> 3)) << 3);
  auto stage = [&](int buf, int ab, int half, int kt) {
    const u16* Mat = ab ? B : A;
    const int ld = ab ? ldb : lda;
    const int tb = ab ? n0 : m0;
#pragma unroll
    for (int j = 0; j < 2; ++j) {
      const int rloc = half * 128 + j * 64 + wave * 8;
      async16(Mat + (long)(tb + rloc + (lane >> 3)) * ld + kt * 64 + sblk,
              (char*)&lds[buf][ab][0] + (rloc << 7));
    }
  };

  bf16x8 af[4][2], bl[2][2], bh[2][2];
  const int aq = lane >> 4;
  auto readA = [&](int buf, int half) {
#pragma unroll
    for (int mf = 0; mf < 4; ++mf) {
      const int rr = half * 128 + wm * 64 + mf * 16 + (lane & 15);
#pragma unroll
      for (int ks = 0; ks < 2; ++ks) {
        const int q2 = ks * 4 + aq;
        af[mf][ks] = *(const bf16x8*)(&lds[buf][0][0] + rr * 64 + ((q2 ^ (rr & 7)) << 3));
      }
    }
  };
  auto readB = [&](int buf, int half, bf16x8 (&bf)[2][2]) {
#pragma unroll
    for (int nf = 0; nf < 2; ++nf) {
      const int rr = half * 128 + wn * 32 + nf * 16 + (lane & 15);
#pragma unroll
      for (int ks = 0; ks < 2; ++ks) {
        const int q2 = ks * 4 + aq;
        bf[nf][ks] = *(const bf16x8*)(&lds[buf][1][0] + rr * 64 + ((q2 ^ (rr & 7)) << 3));
      }
    }
  };

  f32x4 acc[8][4];
#pragma unroll
  for (int i = 0; i < 8; ++i)
#pragma unroll
    for (int j = 0; j < 4; ++j) acc[i][j] = (f32x4){0.f, 0.f, 0.f, 0.f};

#define MFMA16(QM, QN, BF)                                                        \
  __builtin_amdgcn_s_setprio(1);                                                  \
  _Pragma("unroll")                                                               \
  for (int mf = 0; mf < 4; ++mf)                                                  \
    _Pragma("unroll")                                                             \
    for (int nf = 0; nf < 2; ++nf)                                                \
      _Pragma("unroll")                                                           \
      for (int ks = 0; ks < 2; ++ks)                                              \
        acc[(QM)*4+mf][(QN)*2+nf] = __builtin_amdgcn_mfma_f32_16x16x32_bf16(      \
            af[mf][ks], BF[nf][ks], acc[(QM)*4+mf][(QN)*2+nf], 0, 0, 0);          \
  __builtin_amdgcn_s_setprio(0);

#define BAR()   asm volatile("" ::: "memory"); __builtin_amdgcn_s_barrier(); asm volatile("" ::: "memory")
#define WAITV(NN) asm volatile("s_waitcnt vmcnt(" #NN ")" ::: "memory"); __builtin_amdgcn_sched_barrier(0)
#define WAITL(NN) asm volatile("s_waitcnt lgkmcnt(" #NN ")" ::: "memory"); __builtin_amdgcn_sched_barrier(0)

  stage(0, 0, 0, 0); stage(0, 1, 0, 0); stage(0, 1, 1, 0); stage(0, 0, 1, 0);
  stage(1, 0, 0, 1); stage(1, 1, 0, 1); stage(1, 1, 1, 1);
  WAITV(6);
  BAR();
  readB(0, 0, bl);

#define TILE(KTE, BUF)                                                            \
  {                                                                               \
    const int kt = (KTE);                                                         \
    if (kt >= NT - 2) { WAITV(0); } else { WAITV(8); }                            \
    BAR();                                                                        \
    readA(BUF, 0);                                                                \
    readB(BUF, 1, bh);                                                            \
    if (kt + 1 < NT) stage(BUF ^ 1, 0, 1, kt + 1);                                \
    WAITL(4);                                                                     \
    MFMA16(0, 0, bl);                                                             \
    BAR();                                                                        \
    if (kt + 2 < NT) stage(BUF, 0, 0, kt + 2);                                    \
    WAITL(0);                                                                     \
    MFMA16(0, 1, bh);                                                             \
    if (kt >= NT - 2) { WAITV(0); } else { WAITV(10); }                           \
    BAR();                                                                        \
    readA(BUF, 1);                                                                \
    if (kt + 2 < NT) stage(BUF, 1, 0, kt + 2);                                    \
    WAITL(0);                                                                     \
    MFMA16(1, 0, bl);                                                             \
    if (kt >= NT - 2) { WAITV(0); } else { WAITV(8); }                            \
    BAR();                                                                        \
    if (kt + 1 < NT) readB(BUF ^ 1, 0, bl);                                       \
    if (kt + 2 < NT) stage(BUF, 1, 1, kt + 2);                                    \
    WAITL(4);                                                                     \
    MFMA16(1, 1, bh);                                                             \
  }

  for (int kt2 = 0; kt2 < NT; kt2 += 2) {
    TILE(kt2, 0);
    TILE(kt2 + 1, 1);
  }

#pragma unroll
  for (int qm = 0; qm < 2; ++qm)
#pragma unroll
    for (int mf = 0; mf < 4; ++mf)
#pragma unroll
      for (int qn = 0; qn < 2; ++qn)
#pragma unroll
        for (int nf = 0; nf < 2; ++nf) {
          const int col = n0 + qn * 128 + wn * 32 + nf * 16 + (lane & 15);
          if (col >= N) continue;
          const int row0 = m0 + qm * 128 + wm * 64 + mf * 16 + ((lane >> 4) << 2);
          const f32x4 v = acc[qm * 4 + mf][qn * 2 + nf];
#pragma unroll
          for (int rr2 = 0; rr2 < 4; ++rr2)
            C[(long)(row0 + rr2) * N + col] = v[rr2];
        }
#undef TILE
#undef MFMA16
#undef BAR
#undef WAITV
#undef WAITL
}

// ---------------------------------------------------------------- split-K reduce + residual + bf16
__global__ __launch_bounds__(256) void redout_kern(const float* __restrict__ part,
                                                   float* __restrict__ xf,
                                                   u16* __restrict__ xbf) {
  const int i = blockIdx.x * blockDim.x + threadIdx.x;
  if (i >= MROWS * DMODEL / 4) return;
  const int stride4 = MROWS * DMODEL / 4;
  float4 s = ((const float4*)part)[i];
  float4 p1 = ((const float4*)part)[i + stride4];
  float4 p2 = ((const float4*)part)[i + 2 * stride4];
  float4 p3 = ((const float4*)part)[i + 3 * stride4];
  float4 x = ((const float4*)xf)[i];
  s.x += p1.x + p2.x + p3.x + x.x;
  s.y += p1.y + p2.y + p3.y + x.y;
  s.z += p1.z + p2.z + p3.z + x.z;
  s.w += p1.w + p2.w + p3.w + x.w;
  ((float4*)xf)[i] = s;
  ushort4 o; o.x = f2bf(s.x); o.y = f2bf(s.y); o.z = f2bf(s.z); o.w = f2bf(s.w);
  ((ushort4*)xbf)[i] = o;
}

// ---------------------------------------------------------------- fused conv+SiLU+xproj+delta
// xz input is 2 split-K partial slices: value = xz[ix] + xz[ix + XZS]
__global__ __launch_bounds__(256) void convxproj_kern(
    const float* __restrict__ xz, const float* __restrict__ cw,
    const float* __restrict__ Wx, const float* __restrict__ wdt,
    const float* __restrict__ bdt,
    float* __restrict__ xs, float* __restrict__ dlt, float* __restrict__ bc)
{
  __shared__ float sx[DINNER];
  __shared__ float sxp[40];
  const int row = blockIdx.x;
  const int t = row & (SEQ - 1);
  const int tid = threadIdx.x;

  for (int c = tid; c < DINNER; c += 256) {
    const float* w = cw + c * DCONV;
    float a = 0.f;
#pragma unroll
    for (int k = 0; k < DCONV; ++k) {
      const int tt = t - (DCONV - 1) + k;
      if (tt >= 0) {
        const long ix = (long)(row - (DCONV - 1) + k) * (2 * DINNER) + c;
        a += w[k] * (xz[ix] + xz[ix + XZS]);
      }
    }
    const float s = a / (1.f + __expf(-a));
    sx[c] = s;
    xs[(long)row * DINNER + c] = s;
  }
  __syncthreads();

  const int wv = tid >> 6, lane = tid & 63;
  for (int e = wv; e < 2 * DSTATE + 1; e += 4) {
    const float* We = Wx + (long)e * DINNER;
    float p = 0.f;
    for (int d = lane; d < DINNER; d += 64) p += sx[d] * We[d];
#pragma unroll
    for (int off = 32; off; off >>= 1) p += __shfl_xor(p, off, 64);
    if (lane == 0) sxp[e] = p;
  }
  __syncthreads();
  const float dtr = sxp[0];
  for (int d = tid; d < DINNER; d += 256) {
    float v = dtr * wdt[d] + bdt[d];
    float sp = (v > 15.f) ? v : log1pf(__expf(v));
    dlt[(long)row * DINNER + d] = sp;
  }
  if (tid < 2 * DSTATE) bc[(long)row * (2 * DSTATE) + tid] = sxp[1 + tid];
}

// ---------------------------------------------------------------- chunked selective scan + gate
// 256 thr: 8 channels x 32 chunks of 16 steps (R7-proven structure).
__global__ __launch_bounds__(256) void scan_kern(
    const float* __restrict__ dlt, const float* __restrict__ bc,
    const float* __restrict__ xs, const float* __restrict__ xz,
    const float* __restrict__ alog, const float* __restrict__ dpar,
    u16* __restrict__ ybf)
{
  __shared__ float sh_h[32][8][DSTATE];   // 16 KB
  __shared__ float sh_s[32][8];
  const int tid = threadIdx.x;
  const int ch = tid & 7, chunk = tid >> 3;           // chunk 0..31
  const int ch_abs = blockIdx.x * 8 + ch;
  const int b = ch_abs / DINNER, d = ch_abs % DINNER;
  float An[DSTATE];
#pragma unroll
  for (int n = 0; n < DSTATE; ++n) An[n] = -__expf(alog[(long)d * DSTATE + n]);
  const int r0 = b * SEQ + chunk * 16;

  float h[DSTATE];
#pragma unroll
  for (int n = 0; n < DSTATE; ++n) h[n] = 0.f;
  float ssum = 0.f;
  for (int s = 0; s < 16; ++s) {
    const int row = r0 + s;
    const float dl = dlt[(long)row * DINNER + d];
    const float xv = xs[(long)row * DINNER + d];
    const float dx = dl * xv;
    const float4* bp = (const float4*)(bc + (long)row * (2 * DSTATE));
    float Bv[DSTATE];
    *(float4*)&Bv[0] = bp[0]; *(float4*)&Bv[4] = bp[1];
    *(float4*)&Bv[8] = bp[2]; *(float4*)&Bv[12] = bp[3];
    ssum += dl;
#pragma unroll
    for (int n = 0; n < DSTATE; ++n) h[n] = __expf(dl * An[n]) * h[n] + dx * Bv[n];
  }
#pragma unroll
  for (int n = 0; n < DSTATE; ++n) sh_h[chunk][ch][n] = h[n];
  sh_s[chunk][ch] = ssum;
  __syncthreads();

  if (tid < 128) {
    const int n2 = tid & 15, ch2 = tid >> 4;
    const int d2 = (blockIdx.x * 8 + ch2) % DINNER;
    const float A2 = -__expf(alog[(long)d2 * DSTATE + n2]);
    float carry = 0.f;
    for (int c = 0; c < 32; ++c) {
      const float hl = sh_h[c][ch2][n2];
      sh_h[c][ch2][n2] = carry;
      carry = __expf(A2 * sh_s[c][ch2]) * carry + hl;
    }
  }
  __syncthreads();

#pragma unroll
  for (int n = 0; n < DSTATE; ++n) h[n] = sh_h[chunk][ch][n];
  const float dp = dpar[d];
  for (int s = 0; s < 16; ++s) {
    const int row = r0 + s;
    const float dl = dlt[(long)row * DINNER + d];
    const float xv = xs[(long)row * DINNER + d];
    const float dx = dl * xv;
    const float4* bp = (const float4*)(bc + (long)row * (2 * DSTATE));
    float Bv[DSTATE], Cv[DSTATE];
    *(float4*)&Bv[0] = bp[0]; *(float4*)&Bv[4] = bp[1];
    *(float4*)&Bv[8] = bp[2]; *(float4*)&Bv[12] = bp[3];
    *(float4*)&Cv[0] = bp[4]; *(float4*)&Cv[4] = bp[5];
    *(float4*)&Cv[8] = bp[6]; *(float4*)&Cv[12] = bp[7];
    float y = 0.f;
#pragma unroll
    for (int n = 0; n < DSTATE; ++n) {
      const float hn = __expf(dl * An[n]) * h[n] + dx * Bv[n];
      h[n] = hn;
      y += Cv[n] * hn;
    }
    y += dp * xv;
    const long zix = (long)row * (2 * DINNER) + DINNER + d;
    const float zz = xz[zix] + xz[zix + XZS];
    const float o = y * (zz / (1.f + __expf(-zz)));
    ybf[(long)row * DINNER + d] = f2bf(o);
  }
}

// ---------------------------------------------------------------- fused last-redout + RMSNorm -> bf16
__global__ __launch_bounds__(256) void rmsfuse_kern(const float* __restrict__ part,
                                                    const float* __restrict__ xf,
                                                    const float* __restrict__ nw,
                                                    u16* __restrict__ xnbf) {
  const int row = blockIdx.x, tid = threadIdx.x;
  const int S = MROWS * DMODEL;
  float v[3];
  float p = 0.f;
#pragma unroll
  for (int k = 0; k < 3; ++k) {
    const int i = row * DMODEL + tid + k * 256;
    float x = xf[i] + part[i] + part[i + S] + part[i + 2 * S] + part[i + 3 * S];
    v[k] = x;
    p += x * x;
  }
#pragma unroll
  for (int off = 32; off; off >>= 1) p += __shfl_xor(p, off, 64);
  __shared__ float red[4];
  __shared__ float s_rms;
  const int wv = tid >> 6, lane = tid & 63;
  if (lane == 0) red[wv] = p;
  __syncthreads();
  if (tid == 0) {
    float tsum = red[0] + red[1] + red[2] + red[3];
    s_rms = rsqrtf(tsum / (float)DMODEL + 1e-5f);
  }
  __syncthreads();
  const float r = s_rms;
#pragma unroll
  for (int k = 0; k < 3; ++k) {
    const int dd = tid + k * 256;
    xnbf[(long)row * DMODEL + dd] = f2bf(v[k] * r * nw[dd]);
  }
}

// ---------------------------------------------------------------- host
extern "C" void kernel_launch(void* const* d_in, const int* in_sizes, int n_in,
                              void* d_out, int out_size, void* d_ws, size_t ws_size,
                              hipStream_t stream)
{
  (void)in_sizes; (void)n_in; (void)out_size; (void)ws_size;
  const int*   idx   = (const int*)  d_in[0];
  const float* emb   = (const float*)d_in[1];
  const float* W_in  = (const float*)d_in[2];
  const float* convw = (const float*)d_in[3];
  const float* W_xp  = (const float*)d_in[4];
  const float* W_dt  = (const float*)d_in[5];
  const float* b_dt  = (const float*)d_in[6];
  const float* a_log = (const float*)d_in[7];
  const float* d_par = (const float*)d_in[8];
  const float* W_out = (const float*)d_in[9];
  const float* normw = (const float*)d_in[10];
  float* out = (float*)d_out;

  char* ws = (char*)d_ws;
  size_t off = 0;
  auto alloc = [&](size_t bytes) -> void* {
    void* p = ws + off;
    off += (bytes + 255) & ~(size_t)255;
    return p;
  };
  u16*   embbf  = (u16*)  alloc((size_t)VPAD * DMODEL * 2);
  u16*   winbf  = (u16*)  alloc((size_t)NLAYER * 2 * DINNER * DMODEL * 2);
  u16*   woutbf = (u16*)  alloc((size_t)NLAYER * DMODEL * DINNER * 2);
  float* xf     = (float*)alloc((size_t)MROWS * DMODEL * 4);
  u16*   xbf    = (u16*)  alloc((size_t)MROWS * DMODEL * 2);
  float* xz     = (float*)alloc((size_t)2 * MROWS * 2 * DINNER * 4);   // 2 split-K slices
  float* xs     = (float*)alloc((size_t)MROWS * DINNER * 4);
  float* dlt    = (float*)alloc((size_t)MROWS * DINNER * 4);
  float* bc     = (float*)alloc((size_t)MROWS * 2 * DSTATE * 4);
  u16*   ybf    = (u16*)  alloc((size_t)MROWS * DINNER * 2);
  u16*   xnbf   = (u16*)  alloc((size_t)MROWS * DMODEL * 2);
  float* part   = (float*)alloc((size_t)4 * MROWS * DMODEL * 4);

  prep_kern<<<2048, 256, 0, stream>>>(emb, W_in, W_out, idx, embbf, winbf, woutbf, xf, xbf);

  for (int l = 0; l < NLAYER; ++l) {
    // xz = x @ W_in^T, split-K x2 (384 blocks; partial slices xz[0], xz[XZS])
    gemm3_kern<false, true><<<dim3(8 * (2 * DINNER / 128), 1, 2), 256, 0, stream>>>(
        xbf, winbf + (size_t)l * 2 * DINNER * DMODEL, xz,
        MROWS, 2 * DINNER, DMODEL / 2, DMODEL, DMODEL);
    convxproj_kern<<<MROWS, 256, 0, stream>>>(
        xz, convw + (size_t)l * DINNER * DCONV,
        W_xp + (size_t)l * (2 * DSTATE + 1) * DINNER,
        W_dt + (size_t)l * DINNER, b_dt + (size_t)l * DINNER, xs, dlt, bc);
    scan_kern<<<BATCH * DINNER / 8, 256, 0, stream>>>(
        dlt, bc, xs, xz, a_log + (size_t)l * DINNER * DSTATE, d_par + (size_t)l * DINNER, ybf);
    gemm3_kern<false, true><<<dim3(8 * (DMODEL / 128), 1, 4), 256, 0, stream>>>(
        ybf, woutbf + (size_t)l * DMODEL * DINNER, part,
        MROWS, DMODEL, DINNER / 4, DINNER, DINNER);
    if (l < NLAYER - 1)
      redout_kern<<<MROWS * DMODEL / 4 / 256, 256, 0, stream>>>(part, xf, xbf);
  }
  rmsfuse_kern<<<MROWS, 256, 0, stream>>>(part, xf, normw, xnbf);
  gemm8_kern<<<4 * (VPAD / 256), 512, 0, stream>>>(
      xnbf, embbf, out, VV, DMODEL, DMODEL, DMODEL);
}